// Round 10
// baseline (253.334 us; speedup 1.0000x reference)
//
#include <hip/hip_runtime.h>

// ---------------------------------------------------------------------------
// MultiHeadAttention with clipped relative-position embeddings (q/k/v-side).
// B=4, L=1024, D=1024, N=16, H=64, E=64 (127 distinct distances).
//
// Pipeline:
//   0. convert_kernel : fp32->bf16 x; weights -> k-contiguous B^T layouts;
//                       v_emb -> transposed bf16 [64][128]
//   1. gemm<0>        : QKV [4096,1024]@[1024,3072]; q/k [B,N,L,H], v ->
//                       v_t [B,N,H,L] (transposed in scatter epilogue).
//   2. gemm<1> x2     : q_proj/k_proj = q/k @ embed^T; k_proj emits kp_edge
//   3. attn_kernel    : 512-thread blocks (8 waves), QBLK=128, KVBLK=64,
//                       2 blocks/CU resident. T14 split staging + DOUBLE-
//                       buffered Ks/Vt/mj/kpej: prefetch loads issue at top
//                       of tile jt's compute, LDS writes go to buf^1 before
//                       the single end-of-tile barrier (prev readers of
//                       buf^1 were fenced one barrier ago). kp single-buf;
//                       only the 4 kp-prefetch tiles add a pre-write barrier.
//                       s_setprio(1) around MFMA clusters. Register pe bins.
//   4. gemm<2>        : attn_out [4096,1024] @ w_o^T -> d_out fp32
// Workspace: 72.3 MB total (attn_o aliased onto dead x_bf; round-8's
// validated 80.3 MB footprint is the ceiling we stay under).
// ---------------------------------------------------------------------------

typedef __bf16 bf16x8 __attribute__((ext_vector_type(8)));
typedef float f32x4 __attribute__((ext_vector_type(4)));
typedef unsigned int u32x4 __attribute__((ext_vector_type(4)));

__device__ __forceinline__ unsigned short f2bf(float f) {
    unsigned int u = __builtin_bit_cast(unsigned int, f);
    u += 0x7fffu + ((u >> 16) & 1u);          // RNE
    return (unsigned short)(u >> 16);
}
__device__ __forceinline__ float bf2f(unsigned short s) {
    unsigned int u = ((unsigned int)s) << 16;
    return __builtin_bit_cast(float, u);
}

// async global->LDS, 16 bytes per lane; LDS dest must be wave-uniform base
__device__ __forceinline__ void gl2lds16(const unsigned short* g, unsigned short* l) {
    __builtin_amdgcn_global_load_lds(
        (const __attribute__((address_space(1))) unsigned int*)g,
        (__attribute__((address_space(3))) unsigned int*)l, 16, 0, 0);
}

// ---------------------------------------------------------------------------
// Convert / relayout kernel.
// ---------------------------------------------------------------------------
__global__ void convert_kernel(const float* __restrict__ x,
                               const float* __restrict__ wq,
                               const float* __restrict__ wk,
                               const float* __restrict__ wv,
                               const float* __restrict__ wo,
                               const float* __restrict__ qe,
                               const float* __restrict__ ke,
                               const float* __restrict__ ve,
                               unsigned short* __restrict__ x_bf,
                               unsigned short* __restrict__ wqkv_bt,
                               unsigned short* __restrict__ wo_bt,
                               unsigned short* __restrict__ qe_bf,
                               unsigned short* __restrict__ ke_bf,
                               unsigned short* __restrict__ ve_t)
{
    const size_t R0 = 4u * 1024 * 1024;
    const size_t R1 = R0 + 3u * 1024 * 1024;
    const size_t R2 = R1 + 1024u * 1024;
    const size_t R3 = R2 + 8192;
    const size_t R4 = R3 + 8192;
    const size_t R5 = R4 + 8192;
    size_t stride = (size_t)gridDim.x * blockDim.x;
    for (size_t i = (size_t)blockIdx.x * blockDim.x + threadIdx.x; i < R5; i += stride) {
        if (i < R0) {
            x_bf[i] = f2bf(x[i]);
        } else if (i < R1) {
            size_t j = i - R0;
            int which = (int)(j >> 20);
            int rem = (int)(j & 0xFFFFF);
            int n = rem >> 16, d = (rem >> 6) & 1023, h = rem & 63;
            const float* w = which == 0 ? wq : which == 1 ? wk : wv;
            wqkv_bt[(size_t)(which * 1024 + n * 64 + h) * 1024 + d] = f2bf(w[rem]);
        } else if (i < R2) {
            int rem = (int)(i - R1);
            int n = rem >> 16, h = (rem >> 10) & 63, m = rem & 1023;
            wo_bt[(size_t)m * 1024 + n * 64 + h] = f2bf(wo[rem]);
        } else if (i < R3) {
            int idx = (int)(i - R2);
            int e = idx >> 6;
            qe_bf[idx] = (e < 127) ? f2bf(qe[idx]) : 0;
        } else if (i < R4) {
            int idx = (int)(i - R3);
            int e = idx >> 6;
            ke_bf[idx] = (e < 127) ? f2bf(ke[idx]) : 0;
        } else {
            int idx = (int)(i - R4);          // ve transposed: [h=64][e=128]
            int h = idx >> 7, e = idx & 127;
            ve_t[idx] = (e < 127) ? f2bf(ve[e * 64 + h]) : 0;
        }
    }
}

// ---------------------------------------------------------------------------
// 128x128-tile bf16 GEMM, C = A @ Bt^T, m97 staging (global_load_lds x16B,
// linear [128][64] LDS). All row counts multiples of 128 (embed padded).
// MODE 0: scatter -> q/k [B,N,L,H]; v transposed [B,N,H,L]
// MODE 1: bf16 row-major C0; C1 != null: cols 0/126 -> kp_edge[2][65536]
// MODE 2: fp32 row-major C0
// ---------------------------------------------------------------------------
template<int MODE>
__global__ __launch_bounds__(256) void gemm_bt_kernel(
    const unsigned short* __restrict__ A,
    const unsigned short* __restrict__ Bt,
    int K, int lda, int ldb,
    void* __restrict__ C0, void* __restrict__ C1, void* __restrict__ C2,
    int ldc)
{
    __shared__ unsigned short As[128 * 64];
    __shared__ unsigned short Bs[128 * 64];
    const int m0 = blockIdx.y * 128;
    const int n0 = blockIdx.x * 128;
    const int tid = threadIdx.x;
    const int lane = tid & 63;
    const int w = tid >> 6;
    const int wr = w >> 1, wc = w & 1;
    const int g = lane >> 4, c16 = lane & 15;

    f32x4 acc[4][4];
#pragma unroll
    for (int i = 0; i < 4; ++i)
#pragma unroll
        for (int j = 0; j < 4; ++j) acc[i][j] = f32x4{0.f, 0.f, 0.f, 0.f};

    for (int kt = 0; kt < K; kt += 64) {
#pragma unroll
        for (int c = 0; c < 4; ++c) {
            int chunk = c * 256 + tid;           // 1024 chunks of 16B
            int row = chunk >> 3, col = (chunk & 7) * 8;
            unsigned short* ldsA = &As[(c * 256 + w * 64) * 8];   // wave-uniform
            unsigned short* ldsB = &Bs[(c * 256 + w * 64) * 8];
            gl2lds16(A  + (size_t)(m0 + row) * lda + kt + col, ldsA);
            gl2lds16(Bt + (size_t)(n0 + row) * ldb + kt + col, ldsB);
        }
        __syncthreads();
#pragma unroll
        for (int ks = 0; ks < 2; ++ks) {
            bf16x8 af[4], bfr[4];
#pragma unroll
            for (int mi = 0; mi < 4; ++mi)
                af[mi] = __builtin_bit_cast(bf16x8,
                    *reinterpret_cast<const u32x4*>(&As[(wr * 64 + mi * 16 + c16) * 64 + ks * 32 + g * 8]));
#pragma unroll
            for (int ni = 0; ni < 4; ++ni)
                bfr[ni] = __builtin_bit_cast(bf16x8,
                    *reinterpret_cast<const u32x4*>(&Bs[(wc * 64 + ni * 16 + c16) * 64 + ks * 32 + g * 8]));
#pragma unroll
            for (int mi = 0; mi < 4; ++mi)
#pragma unroll
                for (int ni = 0; ni < 4; ++ni)
                    acc[mi][ni] = __builtin_amdgcn_mfma_f32_16x16x32_bf16(af[mi], bfr[ni], acc[mi][ni], 0, 0, 0);
        }
        __syncthreads();
    }

#pragma unroll
    for (int mi = 0; mi < 4; ++mi) {
#pragma unroll
        for (int ni = 0; ni < 4; ++ni) {
#pragma unroll
            for (int r = 0; r < 4; ++r) {
                int m = m0 + wr * 64 + mi * 16 + g * 4 + r;
                int c = n0 + wc * 64 + ni * 16 + c16;
                float v = acc[mi][ni][r];
                if (MODE == 0) {
                    int b = m >> 10, l = m & 1023;
                    int which = c >> 10, n = (c >> 6) & 15, h = c & 63;
                    if (which == 2) {
                        ((unsigned short*)C2)[(((size_t)b * 16 + n) * 64 + h) * 1024 + l] = f2bf(v);
                    } else {
                        unsigned short* dst = (unsigned short*)(which == 0 ? C0 : C1);
                        dst[(((size_t)b * 16 + n) * 1024 + l) * 64 + h] = f2bf(v);
                    }
                } else if (MODE == 1) {
                    ((unsigned short*)C0)[(size_t)m * ldc + c] = f2bf(v);
                    if (C1 && (c == 0 || c == 126))
                        ((unsigned short*)C1)[(size_t)(c ? 65536 : 0) + m] = f2bf(v);
                } else {
                    ((float*)C0)[(size_t)m * ldc + c] = v;
                }
            }
        }
    }
}

// ---------------------------------------------------------------------------
// Fused attention. 512 threads (8 waves), QBLK=128, KVBLK=64.
// Grid 512 (1D): bn = id & 63 (XCD-local group), ib = id >> 6, i0 = ib*128.
// LDS: Ksb[2] [64][72] @0/@9216, Vtb[2] @18432/@27648, Ps[128][72]@36864,
//      kp[64][136]@55296, mj2[2][64]@72704, kpej2[2][64]@73216 -> 73728 B.
// End overlay: veT[64][136]@0, peB[128][136]@17408, lrow[128]@52224.
// Tile jt reads buf jt&1; during tile jt we write buf (jt+1)&1 BEFORE the
// end-of-tile barrier (its previous readers were fenced one barrier ago).
// kp-prefetch tiles (4 of 16) take an extra barrier before the kp write.
// ---------------------------------------------------------------------------
#define ATTN_LDS_BYTES 73728

__global__ __launch_bounds__(512, 4) void attn_kernel(
    const unsigned short* __restrict__ q_buf,   // [B,N,L,H] bf16
    const unsigned short* __restrict__ k_buf,   // [B,N,L,H] bf16
    const unsigned short* __restrict__ v_t,     // [B,N,H,L] bf16
    const unsigned short* __restrict__ q_proj,  // [B,N,L,128] bf16
    const unsigned short* __restrict__ k_proj,  // [B,N,L,128] bf16
    const unsigned short* __restrict__ kp_edge, // [2][65536] bf16 (e=0,126)
    const unsigned short* __restrict__ ve_t,    // [64][128] bf16 (col 127 = 0)
    const int* __restrict__ mask,               // [B,1024]
    unsigned short* __restrict__ attn_out)      // [B,L,N,H] bf16
{
    extern __shared__ char smem[];
    unsigned short* Ps = (unsigned short*)(smem + 36864);  // [128][72]
    unsigned short* kp = (unsigned short*)(smem + 55296);  // [64][136]
    float* mj2   = (float*)(smem + 72704);                 // [2][64]
    float* kpej2 = (float*)(smem + 73216);                 // [2][64]
    unsigned short* veT = (unsigned short*)smem;           // [64][136] overlay
    unsigned short* peB = (unsigned short*)(smem + 17408); // [128][136] overlay
    float* lrow = (float*)(smem + 52224);                  // [128]

    const int id = blockIdx.x;
    const int bn = id & 63;                  // = b*16 + n (same XCD per group)
    const int ib = id >> 6;                  // i-block, 128 rows
    const int b = bn >> 4;
    const int i0 = ib * 128;
    const int tid = threadIdx.x;
    const int lane = tid & 63;
    const int w = tid >> 6;                  // wave 0..7, rows [w*16,w*16+16)
    const int g = lane >> 4, c16 = lane & 15;
    const int il = tid >> 2;                 // histogram row 0..127
    const int part = tid & 3;                // bins [part*32, part*32+32)

    const int jlo = 2 * ib - 1, jhi = 2 * ib + 2;   // kp-staging window

    // staging geometry
    const int sr = tid >> 3,  sc = (tid & 7) * 8;   // K/V: 512 x 16B chunks
    const int kpr = tid >> 4, kpc = (tid & 15) * 8; // kp: 2 x 512 x 16B chunks

    u32x4 kreg, vreg, kpreg0, kpreg1;
    int mjr = 0; unsigned short kper = 0;

    auto issue_loads = [&](int jt, bool wantkp) {
        const int j0 = jt * 64;
        kreg = *reinterpret_cast<const u32x4*>(k_buf + ((size_t)bn * 1024 + j0 + sr) * 64 + sc);
        vreg = *reinterpret_cast<const u32x4*>(v_t + ((size_t)bn * 64 + sr) * 1024 + j0 + sc);
        if (wantkp) {
            kpreg0 = *reinterpret_cast<const u32x4*>(k_proj + ((size_t)bn * 1024 + j0 + kpr) * 128 + kpc);
            kpreg1 = *reinterpret_cast<const u32x4*>(k_proj + ((size_t)bn * 1024 + j0 + 32 + kpr) * 128 + kpc);
        }
        if (tid < 64) {
            mjr = mask[b * 1024 + j0 + tid];
            kper = kp_edge[(size_t)(jt < 2 * ib ? 65536 : 0) + bn * 1024 + j0 + tid];
        }
    };
    auto write_tile = [&](int bufp, bool wantkp) {
        unsigned short* Ksw = (unsigned short*)(smem + bufp * 9216);
        unsigned short* Vtw = (unsigned short*)(smem + 18432 + bufp * 9216);
        *reinterpret_cast<u32x4*>(&Ksw[sr * 72 + sc]) = kreg;
        *reinterpret_cast<u32x4*>(&Vtw[sr * 72 + sc]) = vreg;
        if (wantkp) {
            *reinterpret_cast<u32x4*>(&kp[kpr * 136 + kpc]) = kpreg0;
            *reinterpret_cast<u32x4*>(&kp[(32 + kpr) * 136 + kpc]) = kpreg1;
        }
        if (tid < 64) {
            mj2[bufp * 64 + tid] = mjr ? 1.f : 0.f;
            kpej2[bufp * 64 + tid] = 0.125f * bf2f(kper);
        }
    };

    const bool kp0 = (0 >= jlo && 0 <= jhi);
    issue_loads(0, kp0);

    // Q fragments + loop-invariant qp edge columns (overlap tile-0 latency)
    bf16x8 qf[2];
    {
        const unsigned short* qrow = q_buf + ((size_t)bn * 1024 + i0 + w * 16 + c16) * 64;
        qf[0] = __builtin_bit_cast(bf16x8, *reinterpret_cast<const u32x4*>(qrow + g * 8));
        qf[1] = __builtin_bit_cast(bf16x8, *reinterpret_cast<const u32x4*>(qrow + 32 + g * 8));
    }
    f32x4 qp0v, qp126v;
#pragma unroll
    for (int r = 0; r < 4; ++r) {
        size_t row = (size_t)bn * 1024 + i0 + w * 16 + g * 4 + r;
        qp0v[r]   = 0.125f * bf2f(q_proj[row * 128 + 0]);
        qp126v[r] = 0.125f * bf2f(q_proj[row * 128 + 126]);
    }

    write_tile(0, kp0);
    __syncthreads();

    float peR[32];
#pragma unroll
    for (int k = 0; k < 32; ++k) peR[k] = 0.f;
    float lreg = 0.f, acc0 = 0.f, acc126 = 0.f;
    f32x4 accO[4];
#pragma unroll
    for (int i = 0; i < 4; ++i) accO[i] = f32x4{0.f, 0.f, 0.f, 0.f};

    for (int jt = 0; jt < 16; ++jt) {
        const int cur = jt & 1;
        const int j0 = jt * 64;
        const unsigned short* Ks = (const unsigned short*)(smem + cur * 9216);
        const unsigned short* Vt = (const unsigned short*)(smem + 18432 + cur * 9216);
        const float* mj = &mj2[cur * 64];
        const float* kpej = &kpej2[cur * 64];

        bool nextkp = false;
        if (jt < 15) {                          // prefetch next tile -> regs
            nextkp = (jt + 1 >= jlo) && (jt + 1 <= jhi);
            issue_loads(jt + 1, nextkp);
        }

        // ---- S = Q K^T ----
        f32x4 sacc[4];
#pragma unroll
        for (int nf = 0; nf < 4; ++nf) sacc[nf] = f32x4{0.f, 0.f, 0.f, 0.f};
        __builtin_amdgcn_s_setprio(1);
#pragma unroll
        for (int ks = 0; ks < 2; ++ks)
#pragma unroll
            for (int nf = 0; nf < 4; ++nf) {
                bf16x8 kf = __builtin_bit_cast(bf16x8,
                    *reinterpret_cast<const u32x4*>(&Ks[(nf * 16 + c16) * 72 + ks * 32 + g * 8]));
                sacc[nf] = __builtin_amdgcn_mfma_f32_16x16x32_bf16(qf[ks], kf, sacc[nf], 0, 0, 0);
            }
        __builtin_amdgcn_s_setprio(0);

        // ---- bias + exp + P store (wave-uniform near/far decision) ----
        const int dw = i0 + w * 16 - j0;
        if (dw < 126 && dw > -78) {
            // near: k-side gather from LDS kp, q-side gather from global
            const int d0 = i0 - j0 + 63;
            const unsigned short* qpg = q_proj + ((size_t)bn * 1024 + i0) * 128;
#pragma unroll
            for (int nf = 0; nf < 4; ++nf) {
                int j_l = nf * 16 + c16;
                float mfl = mj[j_l];
#pragma unroll
                for (int r = 0; r < 4; ++r) {
                    int i_l = w * 16 + g * 4 + r;
                    int e = d0 + i_l - j_l;
                    e = e < 0 ? 0 : (e > 126 ? 126 : e);
                    float s = sacc[nf][r] + bf2f(kp[j_l * 136 + e]) + bf2f(qpg[i_l * 128 + e]);
                    s *= 0.125f;
                    float p = (mfl > 0.f) ? __expf(s) : 0.f;
                    Ps[i_l * 72 + j_l] = f2bf(p);
                }
            }
        } else {
            const f32x4 qpc = (dw >= 126) ? qp126v : qp0v;
#pragma unroll
            for (int nf = 0; nf < 4; ++nf) {
                int j_l = nf * 16 + c16;
                float kv = kpej[j_l];
                float mfl = mj[j_l];
#pragma unroll
                for (int r = 0; r < 4; ++r) {
                    float s = sacc[nf][r] * 0.125f + kv + qpc[r];
                    float p = (mfl > 0.f) ? __expf(s) : 0.f;
                    Ps[(w * 16 + g * 4 + r) * 72 + j_l] = f2bf(p);
                }
            }
        }

        // ---- O += P @ V (Ps rows wave-private; lgkmcnt orders RAW) ----
        __builtin_amdgcn_s_setprio(1);
#pragma unroll
        for (int ks = 0; ks < 2; ++ks) {
            bf16x8 pf = __builtin_bit_cast(bf16x8,
                *reinterpret_cast<const u32x4*>(&Ps[(w * 16 + c16) * 72 + ks * 32 + g * 8]));
#pragma unroll
            for (int nf2 = 0; nf2 < 4; ++nf2) {
                bf16x8 vf = __builtin_bit_cast(bf16x8,
                    *reinterpret_cast<const u32x4*>(&Vt[(nf2 * 16 + c16) * 72 + ks * 32 + g * 8]));
                accO[nf2] = __builtin_amdgcn_mfma_f32_16x16x32_bf16(pf, vf, accO[nf2], 0, 0, 0);
            }
        }
        __builtin_amdgcn_s_setprio(0);

        // ---- pe histogram (register bins; per-row near/far) ----
        {
            bf16x8 s0 = __builtin_bit_cast(bf16x8,
                *reinterpret_cast<const u32x4*>(&Ps[il * 72 + part * 16]));
            bf16x8 s1 = __builtin_bit_cast(bf16x8,
                *reinterpret_cast<const u32x4*>(&Ps[il * 72 + part * 16 + 8]));
            float v[16];
#pragma unroll
            for (int m = 0; m < 8; ++m) { v[m] = (float)s0[m]; v[8 + m] = (float)s1[m]; }
            float rs = 0.f;
#pragma unroll
            for (int m = 0; m < 16; ++m) rs += v[m];
            rs += __shfl_xor(rs, 1);
            rs += __shfl_xor(rs, 2);
            lreg += rs;

            const int base = i0 + il - j0 + 63;   // jl for bin e is base - e
            if (base >= 189) {
                acc126 += rs;                     // every e >= 126
            } else if (base <= 0) {
                acc0 += rs;                       // every e <= 0
            } else {
                float b0 = 0.f, b126 = 0.f;
#pragma unroll
                for (int m = 0; m < 16; ++m) {
                    int jl = part * 16 + m;
                    if (jl >= base) b0 += v[m];
                    if (jl <= base - 126) b126 += v[m];
                }
                b0 += __shfl_xor(b0, 1);     b0 += __shfl_xor(b0, 2);
                b126 += __shfl_xor(b126, 1); b126 += __shfl_xor(b126, 2);
                if (part == 0) peR[0] += b0;
                if (part == 3) peR[30] += b126;
#pragma unroll
                for (int k = 0; k < 32; ++k) {
                    int e = part * 32 + k;
                    int jl = base - e;
                    if (e >= 1 && e <= 125 && jl >= 0 && jl < 64)
                        peR[k] += bf2f(Ps[il * 72 + jl]);
                }
            }
        }

        // ---- write next tile's buffers, then the end-of-tile barrier ----
        if (jt < 15) {
            if (nextkp) __syncthreads();     // kp readers (this tile) done
            write_tile(cur ^ 1, nextkp);
            __syncthreads();                 // next buffers visible to all
        } else {
            __syncthreads();                 // fence before end-phase overlay
        }
    }

    if (part == 0) peR[0] += acc0;
    if (part == 3) peR[30] += acc126;

    // ---- end phase: overlay veT/peB/lrow on dead Ks/Vt/Ps/kp ----
#pragma unroll
    for (int c = 0; c < 2; ++c) {
        int chunk = tid + c * 512;           // 1024 chunks of 8 elems = 64x128
        int h = chunk >> 4, col = (chunk & 15) * 8;
        u32x4 vv = *reinterpret_cast<const u32x4*>(ve_t + h * 128 + col);
        *reinterpret_cast<u32x4*>(&veT[h * 136 + col]) = vv;
    }
#pragma unroll
    for (int kk = 0; kk < 4; ++kk) {         // pe spill as bf16
        bf16x8 pk;
#pragma unroll
        for (int e2 = 0; e2 < 8; ++e2) pk[e2] = (__bf16)peR[kk * 8 + e2];
        *reinterpret_cast<u32x4*>(&peB[il * 136 + part * 32 + kk * 8]) =
            __builtin_bit_cast(u32x4, pk);
    }
    if (part == 0) lrow[il] = lreg;
    __syncthreads();

    // O += pe @ veT   (K = 128; col 127 zero on both sides)
#pragma unroll
    for (int ks = 0; ks < 4; ++ks) {
        bf16x8 pf = __builtin_bit_cast(bf16x8,
            *reinterpret_cast<const u32x4*>(&peB[(w * 16 + c16) * 136 + ks * 32 + g * 8]));
#pragma unroll
        for (int nf2 = 0; nf2 < 4; ++nf2) {
            bf16x8 vf = __builtin_bit_cast(bf16x8,
                *reinterpret_cast<const u32x4*>(&veT[(nf2 * 16 + c16) * 136 + ks * 32 + g * 8]));
            accO[nf2] = __builtin_amdgcn_mfma_f32_16x16x32_bf16(pf, vf, accO[nf2], 0, 0, 0);
        }
    }

    // epilogue: attn_out[b, i, n, h] = O / l
#pragma unroll
    for (int nf2 = 0; nf2 < 4; ++nf2) {
#pragma unroll
        for (int r = 0; r < 4; ++r) {
            int i_l = w * 16 + g * 4 + r;
            int h = nf2 * 16 + c16;
            float vv = accO[nf2][r] / lrow[i_l];
            attn_out[(((size_t)b * 1024 + i0 + i_l) * 16 + (bn & 15)) * 64 + h] = f2bf(vv);
        }
    }
}

// ---------------------------------------------------------------------------
extern "C" void kernel_launch(void* const* d_in, const int* in_sizes, int n_in,
                              void* d_out, int out_size, void* d_ws, size_t ws_size,
                              hipStream_t stream)
{
    const float* x  = (const float*)d_in[0];
    const int* mask = (const int*)d_in[1];
    const float* wq = (const float*)d_in[2];
    const float* wk = (const float*)d_in[3];
    const float* wv = (const float*)d_in[4];
    const float* wo = (const float*)d_in[5];
    const float* qe = (const float*)d_in[6];
    const float* ke = (const float*)d_in[7];
    const float* ve = (const float*)d_in[8];

    char* ws = (char*)d_ws;
    size_t off = 0;
    auto carve = [&](size_t bytes) -> char* {
        char* p = ws + off;
        off += (bytes + 255) & ~(size_t)255;
        return p;
    };
    unsigned short* x_bf    = (unsigned short*)carve(4096ull * 1024 * 2);   //  8 MB
    unsigned short* wqkv_bt = (unsigned short*)carve(3072ull * 1024 * 2);   //  6 MB
    unsigned short* wo_bt   = (unsigned short*)carve(1024ull * 1024 * 2);   //  2 MB
    unsigned short* qe_bf   = (unsigned short*)carve(128ull * 64 * 2);
    unsigned short* ke_bf   = (unsigned short*)carve(128ull * 64 * 2);
    unsigned short* ve_t    = (unsigned short*)carve(64ull * 128 * 2);
    unsigned short* q_buf   = (unsigned short*)carve(65536ull * 64 * 2);    //  8 MB
    unsigned short* k_buf   = (unsigned short*)carve(65536ull * 64 * 2);    //  8 MB
    unsigned short* v_t     = (unsigned short*)carve(65536ull * 64 * 2);    //  8 MB
    unsigned short* q_proj  = (unsigned short*)carve(65536ull * 128 * 2);   // 16 MB
    unsigned short* k_proj  = (unsigned short*)carve(65536ull * 128 * 2);   // 16 MB
    unsigned short* kp_edge = (unsigned short*)carve(2ull * 65536 * 2);     // 256 KB
    unsigned short* attn_o  = x_bf;   // alias: x_bf dead after QKV gemm
    (void)ws_size; (void)in_sizes; (void)n_in; (void)out_size;              // ~72.3 MB

    convert_kernel<<<2048, 256, 0, stream>>>(x, wq, wk, wv, wo, qe, ke, ve,
                                             x_bf, wqkv_bt, wo_bt, qe_bf, ke_bf, ve_t);

    // QKV: [4096,1024] @ [1024,3072]; v written transposed
    gemm_bt_kernel<0><<<dim3(24, 32), 256, 0, stream>>>(
        x_bf, wqkv_bt, 1024, 1024, 1024, q_buf, k_buf, v_t, 0);

    // q_proj / k_proj: [65536,64] @ [64,128(127)]
    gemm_bt_kernel<1><<<dim3(1, 512), 256, 0, stream>>>(
        q_buf, qe_bf, 64, 64, 64, q_proj, nullptr, nullptr, 128);
    gemm_bt_kernel<1><<<dim3(1, 512), 256, 0, stream>>>(
        k_buf, ke_bf, 64, 64, 64, k_proj, kp_edge, nullptr, 128);

    // fused attention (8-wave blocks, 2 resident/CU, T14 dbuf prefetch)
    hipFuncSetAttribute((const void*)attn_kernel,
                        hipFuncAttributeMaxDynamicSharedMemorySize, ATTN_LDS_BYTES);
    attn_kernel<<<512, 512, ATTN_LDS_BYTES, stream>>>(
        q_buf, k_buf, v_t, q_proj, k_proj, kp_edge, ve_t, mask, attn_o);

    // output projection: [4096,1024] @ [1024,1024] -> fp32 d_out
    gemm_bt_kernel<2><<<dim3(8, 32), 256, 0, stream>>>(
        attn_o, wo_bt, 1024, 1024, 1024, d_out, nullptr, nullptr, 1024);
}

// Round 11
// 218.490 us; speedup vs baseline: 1.1595x; 1.1595x over previous
//
#include <hip/hip_runtime.h>

// ---------------------------------------------------------------------------
// MultiHeadAttention with clipped relative-position embeddings (q/k/v-side).
// B=4, L=1024, D=1024, N=16, H=64, E=64 (127 distinct distances).
//
// Pipeline:
//   0. convert_kernel : fp32->bf16 x; weights -> k-contiguous B^T layouts;
//                       v_emb -> transposed bf16 [64][128]
//   1. gemm<0>        : QKV [4096,1024]@[1024,3072]; q/k [B,N,L,H], v ->
//                       v_t [B,N,H,L] (transposed in scatter epilogue).
//   2. proj_kernel    : q_proj AND k_proj in ONE launch (1024 blocks);
//                       k half also emits kp_edge cols 0/126.
//   3. attn_kernel    : ROUND-8 VERBATIM (validated 92 us): 512 threads
//                       (8 waves), QBLK=128, KVBLK=64, 2 blocks/CU. Simple
//                       stage->barrier->compute->barrier; kp tile in LDS for
//                       the 4 near-window tiles; far tiles rank-1 bias;
//                       register pe bins. NOTHING held in regs across
//                       compute (round-10's T14/dbuf variant spilled:
//                       WRITE_SIZE 51->129 MB, dur 92->115 us).
//   4. gemm_n64       : out-proj [4096,1024]@[1024,1024] -> fp32, 128x64
//                       tiles, grid 512 = 2 blocks/CU (was 1/CU).
// Workspace 72.3 MB (attn_o aliased onto dead x_bf; validated round 10).
// ---------------------------------------------------------------------------

typedef __bf16 bf16x8 __attribute__((ext_vector_type(8)));
typedef float f32x4 __attribute__((ext_vector_type(4)));
typedef unsigned int u32x4 __attribute__((ext_vector_type(4)));

__device__ __forceinline__ unsigned short f2bf(float f) {
    unsigned int u = __builtin_bit_cast(unsigned int, f);
    u += 0x7fffu + ((u >> 16) & 1u);          // RNE
    return (unsigned short)(u >> 16);
}
__device__ __forceinline__ float bf2f(unsigned short s) {
    unsigned int u = ((unsigned int)s) << 16;
    return __builtin_bit_cast(float, u);
}

// async global->LDS, 16 bytes per lane; LDS dest must be wave-uniform base
__device__ __forceinline__ void gl2lds16(const unsigned short* g, unsigned short* l) {
    __builtin_amdgcn_global_load_lds(
        (const __attribute__((address_space(1))) unsigned int*)g,
        (__attribute__((address_space(3))) unsigned int*)l, 16, 0, 0);
}

// ---------------------------------------------------------------------------
// Convert / relayout kernel.
// ---------------------------------------------------------------------------
__global__ void convert_kernel(const float* __restrict__ x,
                               const float* __restrict__ wq,
                               const float* __restrict__ wk,
                               const float* __restrict__ wv,
                               const float* __restrict__ wo,
                               const float* __restrict__ qe,
                               const float* __restrict__ ke,
                               const float* __restrict__ ve,
                               unsigned short* __restrict__ x_bf,
                               unsigned short* __restrict__ wqkv_bt,
                               unsigned short* __restrict__ wo_bt,
                               unsigned short* __restrict__ qe_bf,
                               unsigned short* __restrict__ ke_bf,
                               unsigned short* __restrict__ ve_t)
{
    const size_t R0 = 4u * 1024 * 1024;
    const size_t R1 = R0 + 3u * 1024 * 1024;
    const size_t R2 = R1 + 1024u * 1024;
    const size_t R3 = R2 + 8192;
    const size_t R4 = R3 + 8192;
    const size_t R5 = R4 + 8192;
    size_t stride = (size_t)gridDim.x * blockDim.x;
    for (size_t i = (size_t)blockIdx.x * blockDim.x + threadIdx.x; i < R5; i += stride) {
        if (i < R0) {
            x_bf[i] = f2bf(x[i]);
        } else if (i < R1) {
            size_t j = i - R0;
            int which = (int)(j >> 20);
            int rem = (int)(j & 0xFFFFF);
            int n = rem >> 16, d = (rem >> 6) & 1023, h = rem & 63;
            const float* w = which == 0 ? wq : which == 1 ? wk : wv;
            wqkv_bt[(size_t)(which * 1024 + n * 64 + h) * 1024 + d] = f2bf(w[rem]);
        } else if (i < R2) {
            int rem = (int)(i - R1);
            int n = rem >> 16, h = (rem >> 10) & 63, m = rem & 1023;
            wo_bt[(size_t)m * 1024 + n * 64 + h] = f2bf(wo[rem]);
        } else if (i < R3) {
            int idx = (int)(i - R2);
            int e = idx >> 6;
            qe_bf[idx] = (e < 127) ? f2bf(qe[idx]) : 0;
        } else if (i < R4) {
            int idx = (int)(i - R3);
            int e = idx >> 6;
            ke_bf[idx] = (e < 127) ? f2bf(ke[idx]) : 0;
        } else {
            int idx = (int)(i - R4);          // ve transposed: [h=64][e=128]
            int h = idx >> 7, e = idx & 127;
            ve_t[idx] = (e < 127) ? f2bf(ve[e * 64 + h]) : 0;
        }
    }
}

// ---------------------------------------------------------------------------
// 128x128-tile bf16 GEMM, C = A @ Bt^T, m97 staging (global_load_lds x16B,
// linear [128][64] LDS). Row counts multiples of 128.
// MODE 0: scatter -> q/k [B,N,L,H]; v transposed [B,N,H,L]
// ---------------------------------------------------------------------------
template<int MODE>
__global__ __launch_bounds__(256) void gemm_bt_kernel(
    const unsigned short* __restrict__ A,
    const unsigned short* __restrict__ Bt,
    int K, int lda, int ldb,
    void* __restrict__ C0, void* __restrict__ C1, void* __restrict__ C2,
    int ldc)
{
    __shared__ unsigned short As[128 * 64];
    __shared__ unsigned short Bs[128 * 64];
    const int m0 = blockIdx.y * 128;
    const int n0 = blockIdx.x * 128;
    const int tid = threadIdx.x;
    const int lane = tid & 63;
    const int w = tid >> 6;
    const int wr = w >> 1, wc = w & 1;
    const int g = lane >> 4, c16 = lane & 15;

    f32x4 acc[4][4];
#pragma unroll
    for (int i = 0; i < 4; ++i)
#pragma unroll
        for (int j = 0; j < 4; ++j) acc[i][j] = f32x4{0.f, 0.f, 0.f, 0.f};

    for (int kt = 0; kt < K; kt += 64) {
#pragma unroll
        for (int c = 0; c < 4; ++c) {
            int chunk = c * 256 + tid;           // 1024 chunks of 16B
            int row = chunk >> 3, col = (chunk & 7) * 8;
            unsigned short* ldsA = &As[(c * 256 + w * 64) * 8];   // wave-uniform
            unsigned short* ldsB = &Bs[(c * 256 + w * 64) * 8];
            gl2lds16(A  + (size_t)(m0 + row) * lda + kt + col, ldsA);
            gl2lds16(Bt + (size_t)(n0 + row) * ldb + kt + col, ldsB);
        }
        __syncthreads();
#pragma unroll
        for (int ks = 0; ks < 2; ++ks) {
            bf16x8 af[4], bfr[4];
#pragma unroll
            for (int mi = 0; mi < 4; ++mi)
                af[mi] = __builtin_bit_cast(bf16x8,
                    *reinterpret_cast<const u32x4*>(&As[(wr * 64 + mi * 16 + c16) * 64 + ks * 32 + g * 8]));
#pragma unroll
            for (int ni = 0; ni < 4; ++ni)
                bfr[ni] = __builtin_bit_cast(bf16x8,
                    *reinterpret_cast<const u32x4*>(&Bs[(wc * 64 + ni * 16 + c16) * 64 + ks * 32 + g * 8]));
#pragma unroll
            for (int mi = 0; mi < 4; ++mi)
#pragma unroll
                for (int ni = 0; ni < 4; ++ni)
                    acc[mi][ni] = __builtin_amdgcn_mfma_f32_16x16x32_bf16(af[mi], bfr[ni], acc[mi][ni], 0, 0, 0);
        }
        __syncthreads();
    }

#pragma unroll
    for (int mi = 0; mi < 4; ++mi) {
#pragma unroll
        for (int ni = 0; ni < 4; ++ni) {
#pragma unroll
            for (int r = 0; r < 4; ++r) {
                int m = m0 + wr * 64 + mi * 16 + g * 4 + r;
                int c = n0 + wc * 64 + ni * 16 + c16;
                float v = acc[mi][ni][r];
                if (MODE == 0) {
                    int b = m >> 10, l = m & 1023;
                    int which = c >> 10, n = (c >> 6) & 15, h = c & 63;
                    if (which == 2) {
                        ((unsigned short*)C2)[(((size_t)b * 16 + n) * 64 + h) * 1024 + l] = f2bf(v);
                    } else {
                        unsigned short* dst = (unsigned short*)(which == 0 ? C0 : C1);
                        dst[(((size_t)b * 16 + n) * 1024 + l) * 64 + h] = f2bf(v);
                    }
                }
            }
        }
    }
}

// ---------------------------------------------------------------------------
// Merged q_proj / k_proj: grid (1, 1024); by<512 -> q, else k (+ kp_edge).
// [65536,64] @ [64,128] per 128-row tile, K=64 (one staging step).
// ---------------------------------------------------------------------------
__global__ __launch_bounds__(256) void proj_kernel(
    const unsigned short* __restrict__ q_buf,
    const unsigned short* __restrict__ k_buf,
    const unsigned short* __restrict__ qe_bf,   // [128][64], row 127 = 0
    const unsigned short* __restrict__ ke_bf,
    unsigned short* __restrict__ q_proj,        // [65536][128]
    unsigned short* __restrict__ k_proj,
    unsigned short* __restrict__ kp_edge)       // [2][65536]
{
    __shared__ unsigned short As[128 * 64];
    __shared__ unsigned short Bs[128 * 64];
    const int by = blockIdx.y;
    const int which = by >> 9;                  // 0 = q, 1 = k
    const int m0 = (by & 511) * 128;
    const unsigned short* A  = which ? k_buf : q_buf;
    const unsigned short* Bt = which ? ke_bf : qe_bf;
    unsigned short* C0 = which ? k_proj : q_proj;

    const int tid = threadIdx.x;
    const int lane = tid & 63;
    const int w = tid >> 6;
    const int wr = w >> 1, wc = w & 1;
    const int g = lane >> 4, c16 = lane & 15;

    f32x4 acc[4][4];
#pragma unroll
    for (int i = 0; i < 4; ++i)
#pragma unroll
        for (int j = 0; j < 4; ++j) acc[i][j] = f32x4{0.f, 0.f, 0.f, 0.f};

#pragma unroll
    for (int c = 0; c < 4; ++c) {
        int chunk = c * 256 + tid;               // 1024 chunks of 16B
        int row = chunk >> 3, col = (chunk & 7) * 8;
        unsigned short* ldsA = &As[(c * 256 + w * 64) * 8];   // wave-uniform
        unsigned short* ldsB = &Bs[(c * 256 + w * 64) * 8];
        gl2lds16(A  + (size_t)(m0 + row) * 64 + col, ldsA);
        gl2lds16(Bt + (size_t)row * 64 + col, ldsB);
    }
    __syncthreads();
#pragma unroll
    for (int ks = 0; ks < 2; ++ks) {
        bf16x8 af[4], bfr[4];
#pragma unroll
        for (int mi = 0; mi < 4; ++mi)
            af[mi] = __builtin_bit_cast(bf16x8,
                *reinterpret_cast<const u32x4*>(&As[(wr * 64 + mi * 16 + c16) * 64 + ks * 32 + g * 8]));
#pragma unroll
        for (int ni = 0; ni < 4; ++ni)
            bfr[ni] = __builtin_bit_cast(bf16x8,
                *reinterpret_cast<const u32x4*>(&Bs[(wc * 64 + ni * 16 + c16) * 64 + ks * 32 + g * 8]));
#pragma unroll
        for (int mi = 0; mi < 4; ++mi)
#pragma unroll
            for (int ni = 0; ni < 4; ++ni)
                acc[mi][ni] = __builtin_amdgcn_mfma_f32_16x16x32_bf16(af[mi], bfr[ni], acc[mi][ni], 0, 0, 0);
    }

#pragma unroll
    for (int mi = 0; mi < 4; ++mi) {
#pragma unroll
        for (int ni = 0; ni < 4; ++ni) {
#pragma unroll
            for (int r = 0; r < 4; ++r) {
                int m = m0 + wr * 64 + mi * 16 + g * 4 + r;
                int c = wc * 64 + ni * 16 + c16;          // n0 = 0, N = 128
                float v = acc[mi][ni][r];
                C0[(size_t)m * 128 + c] = f2bf(v);
                if (which && (c == 0 || c == 126))
                    kp_edge[(size_t)(c ? 65536 : 0) + m] = f2bf(v);
            }
        }
    }
}

// ---------------------------------------------------------------------------
// Out-projection GEMM: [4096,1024] @ wo_bt^T -> fp32, 128x64 tiles.
// Grid (16, 32) = 512 blocks = 2/CU (vs 1/CU for 128x128).
// Wave w owns rows [w*32, w*32+32) x all 64 cols -> acc[2][4].
// ---------------------------------------------------------------------------
__global__ __launch_bounds__(256) void gemm_n64_kernel(
    const unsigned short* __restrict__ A,       // [4096][1024] bf16
    const unsigned short* __restrict__ Bt,      // [1024][1024] bf16
    float* __restrict__ C)                      // [4096][1024] fp32
{
    __shared__ unsigned short As[128 * 64];
    __shared__ unsigned short Bs[64 * 64];
    const int m0 = blockIdx.y * 128;
    const int n0 = blockIdx.x * 64;
    const int tid = threadIdx.x;
    const int lane = tid & 63;
    const int w = tid >> 6;
    const int g = lane >> 4, c16 = lane & 15;

    f32x4 acc[2][4];
#pragma unroll
    for (int i = 0; i < 2; ++i)
#pragma unroll
        for (int j = 0; j < 4; ++j) acc[i][j] = f32x4{0.f, 0.f, 0.f, 0.f};

    for (int kt = 0; kt < 1024; kt += 64) {
#pragma unroll
        for (int c = 0; c < 4; ++c) {            // A: 1024 chunks of 16B
            int chunk = c * 256 + tid;
            int row = chunk >> 3, col = (chunk & 7) * 8;
            unsigned short* ldsA = &As[(c * 256 + w * 64) * 8];
            gl2lds16(A + (size_t)(m0 + row) * 1024 + kt + col, ldsA);
        }
#pragma unroll
        for (int c = 0; c < 2; ++c) {            // B: 512 chunks of 16B
            int chunk = c * 256 + tid;
            int row = chunk >> 3, col = (chunk & 7) * 8;
            unsigned short* ldsB = &Bs[(c * 256 + w * 64) * 8];
            gl2lds16(Bt + (size_t)(n0 + row) * 1024 + kt + col, ldsB);
        }
        __syncthreads();
#pragma unroll
        for (int ks = 0; ks < 2; ++ks) {
            bf16x8 af[2], bfr[4];
#pragma unroll
            for (int mi = 0; mi < 2; ++mi)
                af[mi] = __builtin_bit_cast(bf16x8,
                    *reinterpret_cast<const u32x4*>(&As[(w * 32 + mi * 16 + c16) * 64 + ks * 32 + g * 8]));
#pragma unroll
            for (int ni = 0; ni < 4; ++ni)
                bfr[ni] = __builtin_bit_cast(bf16x8,
                    *reinterpret_cast<const u32x4*>(&Bs[(ni * 16 + c16) * 64 + ks * 32 + g * 8]));
#pragma unroll
            for (int mi = 0; mi < 2; ++mi)
#pragma unroll
                for (int ni = 0; ni < 4; ++ni)
                    acc[mi][ni] = __builtin_amdgcn_mfma_f32_16x16x32_bf16(af[mi], bfr[ni], acc[mi][ni], 0, 0, 0);
        }
        __syncthreads();
    }

#pragma unroll
    for (int mi = 0; mi < 2; ++mi)
#pragma unroll
        for (int ni = 0; ni < 4; ++ni)
#pragma unroll
            for (int r = 0; r < 4; ++r) {
                int m = m0 + w * 32 + mi * 16 + g * 4 + r;
                int cc = n0 + ni * 16 + c16;
                C[(size_t)m * 1024 + cc] = acc[mi][ni][r];
            }
}

// ---------------------------------------------------------------------------
// Fused attention — ROUND-8 VERBATIM (validated 92 us steady-state).
// 512 threads (8 waves), QBLK=128, KVBLK=64.
// Grid 512 (1D): bn = id & 63 (XCD-local group), ib = id >> 6, i0 = ib*128.
// LDS: Ks[64][72]@0, Vt[64][72]@9216, Ps[128][72]@18432, kp[64][136]@36864,
//      mj[64]f32@54272, kpej[64]f32@54528 -> 54784 B.
// End overlay: veT[64][136]@0, peB[128][136]@17408, lrow[128]@52224.
// ---------------------------------------------------------------------------
#define ATTN_LDS_BYTES 54784

__global__ __launch_bounds__(512, 4) void attn_kernel(
    const unsigned short* __restrict__ q_buf,   // [B,N,L,H] bf16
    const unsigned short* __restrict__ k_buf,   // [B,N,L,H] bf16
    const unsigned short* __restrict__ v_t,     // [B,N,H,L] bf16
    const unsigned short* __restrict__ q_proj,  // [B,N,L,128] bf16
    const unsigned short* __restrict__ k_proj,  // [B,N,L,128] bf16
    const unsigned short* __restrict__ kp_edge, // [2][65536] bf16 (e=0,126)
    const unsigned short* __restrict__ ve_t,    // [64][128] bf16 (col 127 = 0)
    const int* __restrict__ mask,               // [B,1024]
    unsigned short* __restrict__ attn_out)      // [B,L,N,H] bf16
{
    extern __shared__ char smem[];
    unsigned short* Ks = (unsigned short*)smem;            // [64][72]
    unsigned short* Vt = (unsigned short*)(smem + 9216);   // [64][72]
    unsigned short* Ps = (unsigned short*)(smem + 18432);  // [128][72]
    unsigned short* kp = (unsigned short*)(smem + 36864);  // [64][136]
    float* mj   = (float*)(smem + 54272);                  // [64]
    float* kpej = (float*)(smem + 54528);                  // [64]
    unsigned short* veT = (unsigned short*)smem;           // [64][136] overlay
    unsigned short* peB = (unsigned short*)(smem + 17408); // [128][136] overlay
    float* lrow = (float*)(smem + 52224);                  // [128]

    const int id = blockIdx.x;
    const int bn = id & 63;                  // = b*16 + n (same XCD per group)
    const int ib = id >> 6;                  // i-block, 128 rows
    const int b = bn >> 4;
    const int i0 = ib * 128;
    const int tid = threadIdx.x;
    const int lane = tid & 63;
    const int w = tid >> 6;                  // wave 0..7, rows [w*16,w*16+16)
    const int g = lane >> 4, c16 = lane & 15;
    const int il = tid >> 2;                 // histogram row 0..127
    const int part = tid & 3;                // bins [part*32, part*32+32)

    const int jlo = 2 * ib - 1, jhi = 2 * ib + 2;   // kp-staging window

    // staging geometry
    const int sr = tid >> 3,  sc = (tid & 7) * 8;   // K/V: 512 x 16B chunks

    // Q fragments (A-row = c16), k-slot = ks*32 + 8g + slot
    bf16x8 qf[2];
    {
        const unsigned short* qrow = q_buf + ((size_t)bn * 1024 + i0 + w * 16 + c16) * 64;
        qf[0] = __builtin_bit_cast(bf16x8, *reinterpret_cast<const u32x4*>(qrow + g * 8));
        qf[1] = __builtin_bit_cast(bf16x8, *reinterpret_cast<const u32x4*>(qrow + 32 + g * 8));
    }
    // loop-invariant far-tile qp edge columns (global, 8 scalar loads)
    f32x4 qp0v, qp126v;
#pragma unroll
    for (int r = 0; r < 4; ++r) {
        size_t row = (size_t)bn * 1024 + i0 + w * 16 + g * 4 + r;
        qp0v[r]   = 0.125f * bf2f(q_proj[row * 128 + 0]);
        qp126v[r] = 0.125f * bf2f(q_proj[row * 128 + 126]);
    }

    float peR[32];
#pragma unroll
    for (int k = 0; k < 32; ++k) peR[k] = 0.f;
    float lreg = 0.f, acc0 = 0.f, acc126 = 0.f;
    f32x4 accO[4];
#pragma unroll
    for (int i = 0; i < 4; ++i) accO[i] = f32x4{0.f, 0.f, 0.f, 0.f};

    for (int jt = 0; jt < 16; ++jt) {
        const int j0 = jt * 64;
        const bool need_kp = (jt >= jlo) && (jt <= jhi);

        // ---- stage K, V^T (+ kp when near-union), mask, far edge bias ----
        {
            u32x4 kv = *reinterpret_cast<const u32x4*>(k_buf + ((size_t)bn * 1024 + j0 + sr) * 64 + sc);
            u32x4 vv = *reinterpret_cast<const u32x4*>(v_t + ((size_t)bn * 64 + sr) * 1024 + j0 + sc);
            *reinterpret_cast<u32x4*>(&Ks[sr * 72 + sc]) = kv;
            *reinterpret_cast<u32x4*>(&Vt[sr * 72 + sc]) = vv;
        }
        if (need_kp) {
#pragma unroll
            for (int c = 0; c < 2; ++c) {
                int chunk = tid + c * 512;        // 1024 chunks of 8 elems
                int row = chunk >> 4, col = (chunk & 15) * 8;
                u32x4 v = *reinterpret_cast<const u32x4*>(k_proj + ((size_t)bn * 1024 + j0 + row) * 128 + col);
                *reinterpret_cast<u32x4*>(&kp[row * 136 + col]) = v;
            }
        }
        if (tid < 64) {
            mj[tid] = mask[b * 1024 + j0 + tid] ? 1.f : 0.f;
            // far-plane: tiles left of the i-block use e=126, right use e=0
            kpej[tid] = 0.125f * bf2f(kp_edge[(size_t)(jt < 2 * ib ? 65536 : 0) + bn * 1024 + j0 + tid]);
        }
        __syncthreads();

        // ---- S = Q K^T ----
        f32x4 sacc[4];
#pragma unroll
        for (int nf = 0; nf < 4; ++nf) sacc[nf] = f32x4{0.f, 0.f, 0.f, 0.f};
#pragma unroll
        for (int ks = 0; ks < 2; ++ks)
#pragma unroll
            for (int nf = 0; nf < 4; ++nf) {
                bf16x8 kf = __builtin_bit_cast(bf16x8,
                    *reinterpret_cast<const u32x4*>(&Ks[(nf * 16 + c16) * 72 + ks * 32 + g * 8]));
                sacc[nf] = __builtin_amdgcn_mfma_f32_16x16x32_bf16(qf[ks], kf, sacc[nf], 0, 0, 0);
            }

        // ---- bias + exp + P store (wave-uniform near/far decision) ----
        const int dw = i0 + w * 16 - j0;
        if (dw < 126 && dw > -78) {
            // near: k-side gather from LDS kp, q-side gather from global
            const int d0 = i0 - j0 + 63;
            const unsigned short* qpg = q_proj + ((size_t)bn * 1024 + i0) * 128;
#pragma unroll
            for (int nf = 0; nf < 4; ++nf) {
                int j_l = nf * 16 + c16;
                float mfl = mj[j_l];
#pragma unroll
                for (int r = 0; r < 4; ++r) {
                    int i_l = w * 16 + g * 4 + r;
                    int e = d0 + i_l - j_l;
                    e = e < 0 ? 0 : (e > 126 ? 126 : e);
                    float s = sacc[nf][r] + bf2f(kp[j_l * 136 + e]) + bf2f(qpg[i_l * 128 + e]);
                    s *= 0.125f;
                    float p = (mfl > 0.f) ? __expf(s) : 0.f;
                    Ps[i_l * 72 + j_l] = f2bf(p);
                }
            }
        } else {
            const f32x4 qpc = (dw >= 126) ? qp126v : qp0v;
#pragma unroll
            for (int nf = 0; nf < 4; ++nf) {
                int j_l = nf * 16 + c16;
                float kv = kpej[j_l];
                float mfl = mj[j_l];
#pragma unroll
                for (int r = 0; r < 4; ++r) {
                    float s = sacc[nf][r] * 0.125f + kv + qpc[r];
                    float p = (mfl > 0.f) ? __expf(s) : 0.f;
                    Ps[(w * 16 + g * 4 + r) * 72 + j_l] = f2bf(p);
                }
            }
        }

        // ---- O += P @ V (Ps rows wave-private; lgkmcnt orders RAW) ----
#pragma unroll
        for (int ks = 0; ks < 2; ++ks) {
            bf16x8 pf = __builtin_bit_cast(bf16x8,
                *reinterpret_cast<const u32x4*>(&Ps[(w * 16 + c16) * 72 + ks * 32 + g * 8]));
#pragma unroll
            for (int nf2 = 0; nf2 < 4; ++nf2) {
                bf16x8 vf = __builtin_bit_cast(bf16x8,
                    *reinterpret_cast<const u32x4*>(&Vt[(nf2 * 16 + c16) * 72 + ks * 32 + g * 8]));
                accO[nf2] = __builtin_amdgcn_mfma_f32_16x16x32_bf16(pf, vf, accO[nf2], 0, 0, 0);
            }
        }

        // ---- pe histogram (register bins; per-row near/far) ----
        {
            bf16x8 s0 = __builtin_bit_cast(bf16x8,
                *reinterpret_cast<const u32x4*>(&Ps[il * 72 + part * 16]));
            bf16x8 s1 = __builtin_bit_cast(bf16x8,
                *reinterpret_cast<const u32x4*>(&Ps[il * 72 + part * 16 + 8]));
            float v[16];
#pragma unroll
            for (int m = 0; m < 8; ++m) { v[m] = (float)s0[m]; v[8 + m] = (float)s1[m]; }
            float rs = 0.f;
#pragma unroll
            for (int m = 0; m < 16; ++m) rs += v[m];
            rs += __shfl_xor(rs, 1);
            rs += __shfl_xor(rs, 2);
            lreg += rs;

            const int base = i0 + il - j0 + 63;   // jl for bin e is base - e
            if (base >= 189) {
                acc126 += rs;                     // every e >= 126
            } else if (base <= 0) {
                acc0 += rs;                       // every e <= 0
            } else {
                float b0 = 0.f, b126 = 0.f;
#pragma unroll
                for (int m = 0; m < 16; ++m) {
                    int jl = part * 16 + m;
                    if (jl >= base) b0 += v[m];
                    if (jl <= base - 126) b126 += v[m];
                }
                b0 += __shfl_xor(b0, 1);     b0 += __shfl_xor(b0, 2);
                b126 += __shfl_xor(b126, 1); b126 += __shfl_xor(b126, 2);
                if (part == 0) peR[0] += b0;
                if (part == 3) peR[30] += b126;
#pragma unroll
                for (int k = 0; k < 32; ++k) {
                    int e = part * 32 + k;
                    int jl = base - e;
                    if (e >= 1 && e <= 125 && jl >= 0 && jl < 64)
                        peR[k] += bf2f(Ps[il * 72 + jl]);
                }
            }
        }
        __syncthreads();                     // all waves done with Ks/Vt/kp
    }

    if (part == 0) peR[0] += acc0;
    if (part == 3) peR[30] += acc126;

    // ---- end phase: overlay veT/peB/lrow on dead Ks/Vt/Ps/kp ----
#pragma unroll
    for (int c = 0; c < 2; ++c) {
        int chunk = tid + c * 512;           // 1024 chunks of 8 elems = 64x128
        int h = chunk >> 4, col = (chunk & 15) * 8;
        u32x4 vv = *reinterpret_cast<const u32x4*>(ve_t + h * 128 + col);
        *reinterpret_cast<u32x4*>(&veT[h * 136 + col]) = vv;
    }
#pragma unroll
    for (int kk = 0; kk < 4; ++kk) {         // pe spill as bf16
        bf16x8 pk;
#pragma unroll
        for (int e2 = 0; e2 < 8; ++e2) pk[e2] = (__bf16)peR[kk * 8 + e2];
        *reinterpret_cast<u32x4*>(&peB[il * 136 + part * 32 + kk * 8]) =
            __builtin_bit_cast(u32x4, pk);
    }
    if (part == 0) lrow[il] = lreg;
    __syncthreads();

    // O += pe @ veT   (K = 128; col 127 zero on both sides)
#pragma unroll
    for (int ks = 0; ks < 4; ++ks) {
        bf16x8 pf = __builtin_bit_cast(bf16x8,
            *reinterpret_cast<const u32x4*>(&peB[(w * 16 + c16) * 136 + ks * 32 + g * 8]));
#pragma unroll
        for (int nf2 = 0; nf2 < 4; ++nf2) {
            bf16x8 vf = __builtin_bit_cast(bf16x8,
                *reinterpret_cast<const u32x4*>(&veT[(nf2 * 16 + c16) * 136 + ks * 32 + g * 8]));
            accO[nf2] = __builtin_amdgcn_mfma_f32_16x16x32_bf16(pf, vf, accO[nf2], 0, 0, 0);
        }
    }

    // epilogue: attn_out[b, i, n, h] = O / l
#pragma unroll
    for (int nf2 = 0; nf2 < 4; ++nf2) {
#pragma unroll
        for (int r = 0; r < 4; ++r) {
            int i_l = w * 16 + g * 4 + r;
            int h = nf2 * 16 + c16;
            float vv = accO[nf2][r] / lrow[i_l];
            attn_out[(((size_t)b * 1024 + i0 + i_l) * 16 + (bn & 15)) * 64 + h] = f2bf(vv);
        }
    }
}

// ---------------------------------------------------------------------------
extern "C" void kernel_launch(void* const* d_in, const int* in_sizes, int n_in,
                              void* d_out, int out_size, void* d_ws, size_t ws_size,
                              hipStream_t stream)
{
    const float* x  = (const float*)d_in[0];
    const int* mask = (const int*)d_in[1];
    const float* wq = (const float*)d_in[2];
    const float* wk = (const float*)d_in[3];
    const float* wv = (const float*)d_in[4];
    const float* wo = (const float*)d_in[5];
    const float* qe = (const float*)d_in[6];
    const float* ke = (const float*)d_in[7];
    const float* ve = (const float*)d_in[8];

    char* ws = (char*)d_ws;
    size_t off = 0;
    auto carve = [&](size_t bytes) -> char* {
        char* p = ws + off;
        off += (bytes + 255) & ~(size_t)255;
        return p;
    };
    unsigned short* x_bf    = (unsigned short*)carve(4096ull * 1024 * 2);   //  8 MB
    unsigned short* wqkv_bt = (unsigned short*)carve(3072ull * 1024 * 2);   //  6 MB
    unsigned short* wo_bt   = (unsigned short*)carve(1024ull * 1024 * 2);   //  2 MB
    unsigned short* qe_bf   = (unsigned short*)carve(128ull * 64 * 2);
    unsigned short* ke_bf   = (unsigned short*)carve(128ull * 64 * 2);
    unsigned short* ve_t    = (unsigned short*)carve(64ull * 128 * 2);
    unsigned short* q_buf   = (unsigned short*)carve(65536ull * 64 * 2);    //  8 MB
    unsigned short* k_buf   = (unsigned short*)carve(65536ull * 64 * 2);    //  8 MB
    unsigned short* v_t     = (unsigned short*)carve(65536ull * 64 * 2);    //  8 MB
    unsigned short* q_proj  = (unsigned short*)carve(65536ull * 128 * 2);   // 16 MB
    unsigned short* k_proj  = (unsigned short*)carve(65536ull * 128 * 2);   // 16 MB
    unsigned short* kp_edge = (unsigned short*)carve(2ull * 65536 * 2);     // 256 KB
    unsigned short* attn_o  = x_bf;   // alias: x_bf dead after QKV gemm
    (void)ws_size; (void)in_sizes; (void)n_in; (void)out_size;              // ~72.3 MB

    convert_kernel<<<2048, 256, 0, stream>>>(x, wq, wk, wv, wo, qe, ke, ve,
                                             x_bf, wqkv_bt, wo_bt, qe_bf, ke_bf, ve_t);

    // QKV: [4096,1024] @ [1024,3072]; v written transposed
    gemm_bt_kernel<0><<<dim3(24, 32), 256, 0, stream>>>(
        x_bf, wqkv_bt, 1024, 1024, 1024, q_buf, k_buf, v_t, 0);

    // merged q_proj + k_proj (+ kp_edge): one 1024-block launch
    proj_kernel<<<dim3(1, 1024), 256, 0, stream>>>(
        q_buf, k_buf, qe_bf, ke_bf, q_proj, k_proj, kp_edge);

    // fused attention (round-8 verbatim; 8-wave blocks, 2 resident/CU)
    hipFuncSetAttribute((const void*)attn_kernel,
                        hipFuncAttributeMaxDynamicSharedMemorySize, ATTN_LDS_BYTES);
    attn_kernel<<<512, 512, ATTN_LDS_BYTES, stream>>>(
        q_buf, k_buf, v_t, q_proj, k_proj, kp_edge, ve_t, mask, attn_o);

    // output projection: 128x64 tiles, 512 blocks = 2/CU
    gemm_n64_kernel<<<dim3(16, 32), 256, 0, stream>>>(attn_o, wo_bt, (float*)d_out);
}

// Round 12
// 192.800 us; speedup vs baseline: 1.3140x; 1.1332x over previous
//
#include <hip/hip_runtime.h>

// ---------------------------------------------------------------------------
// MultiHeadAttention with clipped relative-position embeddings (q/k/v-side).
// B=4, L=1024, D=1024, N=16, H=64, E=64 (127 distinct distances).
//
// Pipeline:
//   0. convert_kernel : region-dispatched, all-coalesced:
//                       [0,512)    x f32->bf16, f32x4 vectorized
//                       [512,1280) wqkv 64x64 LDS-tile transpose (coalesced
//                                  read AND write; was 2B-scatter)
//                       [1280,1536) wo 64x64 LDS-tile transpose
//                       [1536]     qe/ke/ve tables
//   1. gemm_qkv       : [4096,1024]@[1024,3072]; q/k coalesced scatter;
//                       v-blocks transpose through reused As/Bs LDS ->
//                       v_t [B,N,H,L] written 16B-coalesced (was 2B-scatter)
//   2. proj_kernel    : q_proj AND k_proj in one launch (+ kp_edge)
//   3. attn_kernel    : ROUND-8 VERBATIM (validated 92 us; not touched)
//   4. gemm_n64       : out-proj 128x64 tiles -> fp32 d_out
// Workspace 72.3 MB (attn_o aliased onto dead x_bf; validated).
// ---------------------------------------------------------------------------

typedef __bf16 bf16x8 __attribute__((ext_vector_type(8)));
typedef float f32x4 __attribute__((ext_vector_type(4)));
typedef unsigned int u32x4 __attribute__((ext_vector_type(4)));
typedef unsigned short u16x4 __attribute__((ext_vector_type(4)));

__device__ __forceinline__ unsigned short f2bf(float f) {
    unsigned int u = __builtin_bit_cast(unsigned int, f);
    u += 0x7fffu + ((u >> 16) & 1u);          // RNE
    return (unsigned short)(u >> 16);
}
__device__ __forceinline__ float bf2f(unsigned short s) {
    unsigned int u = ((unsigned int)s) << 16;
    return __builtin_bit_cast(float, u);
}

// async global->LDS, 16 bytes per lane; LDS dest must be wave-uniform base
__device__ __forceinline__ void gl2lds16(const unsigned short* g, unsigned short* l) {
    __builtin_amdgcn_global_load_lds(
        (const __attribute__((address_space(1))) unsigned int*)g,
        (__attribute__((address_space(3))) unsigned int*)l, 16, 0, 0);
}

// ---------------------------------------------------------------------------
// Convert / relayout kernel — all regions coalesced.
// ---------------------------------------------------------------------------
__global__ __launch_bounds__(256) void convert_kernel(
    const float* __restrict__ x,
    const float* __restrict__ wq,
    const float* __restrict__ wk,
    const float* __restrict__ wv,
    const float* __restrict__ wo,
    const float* __restrict__ qe,
    const float* __restrict__ ke,
    const float* __restrict__ ve,
    unsigned short* __restrict__ x_bf,
    unsigned short* __restrict__ wqkv_bt,
    unsigned short* __restrict__ wo_bt,
    unsigned short* __restrict__ qe_bf,
    unsigned short* __restrict__ ke_bf,
    unsigned short* __restrict__ ve_t)
{
    __shared__ unsigned short T[64 * 72];
    const int bid = blockIdx.x;
    const int tid = threadIdx.x;

    if (bid < 512) {
        // x: 4M f32 -> bf16, 8192 per block, f32x4 vectorized
        const float* src = x + (size_t)bid * 8192;
        unsigned short* dst = x_bf + (size_t)bid * 8192;
#pragma unroll
        for (int c = 0; c < 8; ++c) {
            int idx = c * 1024 + tid * 4;
            f32x4 v = *reinterpret_cast<const f32x4*>(src + idx);
            u16x4 o = u16x4{f2bf(v[0]), f2bf(v[1]), f2bf(v[2]), f2bf(v[3])};
            *reinterpret_cast<u16x4*>(dst + idx) = o;
        }
    } else if (bid < 1280) {
        // wqkv: w[n][d][h] -> wqkv_bt[(which*1024+n*64+h)][d], 64x64 tiles
        int t = bid - 512;
        int which = t >> 8, n = (t >> 4) & 15, dt = t & 15;
        const float* w = which == 0 ? wq : which == 1 ? wk : wv;
        const float* src = w + ((size_t)n * 1024 + dt * 64) * 64;   // [dd][hh]
#pragma unroll
        for (int c = 0; c < 4; ++c) {
            int chunk = c * 256 + tid;             // 1024 chunks of 4 f32
            int dd = chunk >> 4, hh = (chunk & 15) * 4;
            f32x4 v = *reinterpret_cast<const f32x4*>(src + dd * 64 + hh);
#pragma unroll
            for (int j = 0; j < 4; ++j) T[(hh + j) * 72 + dd] = f2bf(v[j]);
        }
        __syncthreads();
        unsigned short* dstb = wqkv_bt + ((size_t)(which * 1024 + n * 64)) * 1024 + dt * 64;
#pragma unroll
        for (int c = 0; c < 2; ++c) {
            int chunk = c * 256 + tid;             // 512 chunks of 8
            int h = chunk >> 3, d8 = (chunk & 7) * 8;
            u32x4 v = *reinterpret_cast<const u32x4*>(&T[h * 72 + d8]);
            *reinterpret_cast<u32x4*>(dstb + (size_t)h * 1024 + d8) = v;
        }
    } else if (bid < 1536) {
        // wo: wo[n][h][m] -> wo_bt[m][n*64+h], 64x64 tiles
        int t = bid - 1280;
        int n = t >> 4, mt = t & 15;
        const float* src = wo + (size_t)n * 64 * 1024 + mt * 64;    // [hh][mm]
#pragma unroll
        for (int c = 0; c < 4; ++c) {
            int chunk = c * 256 + tid;             // 1024 chunks of 4 f32
            int hh = chunk >> 4, mm = (chunk & 15) * 4;
            f32x4 v = *reinterpret_cast<const f32x4*>(src + (size_t)hh * 1024 + mm);
#pragma unroll
            for (int j = 0; j < 4; ++j) T[(mm + j) * 72 + hh] = f2bf(v[j]);
        }
        __syncthreads();
        unsigned short* dstb = wo_bt + (size_t)(mt * 64) * 1024 + n * 64;
#pragma unroll
        for (int c = 0; c < 2; ++c) {
            int chunk = c * 256 + tid;             // 512 chunks of 8
            int m = chunk >> 3, h8 = (chunk & 7) * 8;
            u32x4 v = *reinterpret_cast<const u32x4*>(&T[m * 72 + h8]);
            *reinterpret_cast<u32x4*>(dstb + (size_t)m * 1024 + h8) = v;
        }
    } else {
        // tables: qe/ke [128][64] (row 127 zero); ve_t [64][128] (col 127 zero)
        for (int i = tid; i < 8192; i += 256) {
            int e = i >> 6;
            qe_bf[i] = (e < 127) ? f2bf(qe[i]) : 0;
            ke_bf[i] = (e < 127) ? f2bf(ke[i]) : 0;
            int h = i >> 7, e2 = i & 127;
            ve_t[i] = (e2 < 127) ? f2bf(ve[e2 * 64 + h]) : 0;
        }
    }
}

// ---------------------------------------------------------------------------
// QKV GEMM: [4096,1024] @ [1024,3072], m97 staging. q/k blocks: coalesced
// h-contiguous scatter. v blocks (n0 >= 2048): route epilogue through a
// 128x128 LDS transpose (reusing As|Bs = 32 KB) -> v_t 16B-coalesced.
// XOR swizzle l^((c&7)<<3) keeps 8-runs contiguous and writes conflict-low.
// ---------------------------------------------------------------------------
__global__ __launch_bounds__(256) void gemm_qkv_kernel(
    const unsigned short* __restrict__ A,
    const unsigned short* __restrict__ Bt,
    unsigned short* __restrict__ q_buf,
    unsigned short* __restrict__ k_buf,
    unsigned short* __restrict__ v_t)
{
    __shared__ unsigned short Sh[2 * 128 * 64];    // As | Bs; reused as T[128][128]
    unsigned short* As = Sh;
    unsigned short* Bs = Sh + 8192;
    const int m0 = blockIdx.y * 128;
    const int n0 = blockIdx.x * 128;
    const int tid = threadIdx.x;
    const int lane = tid & 63;
    const int w = tid >> 6;
    const int wr = w >> 1, wc = w & 1;
    const int g = lane >> 4, c16 = lane & 15;

    f32x4 acc[4][4];
#pragma unroll
    for (int i = 0; i < 4; ++i)
#pragma unroll
        for (int j = 0; j < 4; ++j) acc[i][j] = f32x4{0.f, 0.f, 0.f, 0.f};

    for (int kt = 0; kt < 1024; kt += 64) {
#pragma unroll
        for (int c = 0; c < 4; ++c) {
            int chunk = c * 256 + tid;           // 1024 chunks of 16B
            int row = chunk >> 3, col = (chunk & 7) * 8;
            unsigned short* ldsA = &As[(c * 256 + w * 64) * 8];   // wave-uniform
            unsigned short* ldsB = &Bs[(c * 256 + w * 64) * 8];
            gl2lds16(A  + (size_t)(m0 + row) * 1024 + kt + col, ldsA);
            gl2lds16(Bt + (size_t)(n0 + row) * 1024 + kt + col, ldsB);
        }
        __syncthreads();
#pragma unroll
        for (int ks = 0; ks < 2; ++ks) {
            bf16x8 af[4], bfr[4];
#pragma unroll
            for (int mi = 0; mi < 4; ++mi)
                af[mi] = __builtin_bit_cast(bf16x8,
                    *reinterpret_cast<const u32x4*>(&As[(wr * 64 + mi * 16 + c16) * 64 + ks * 32 + g * 8]));
#pragma unroll
            for (int ni = 0; ni < 4; ++ni)
                bfr[ni] = __builtin_bit_cast(bf16x8,
                    *reinterpret_cast<const u32x4*>(&Bs[(wc * 64 + ni * 16 + c16) * 64 + ks * 32 + g * 8]));
#pragma unroll
            for (int mi = 0; mi < 4; ++mi)
#pragma unroll
                for (int ni = 0; ni < 4; ++ni)
                    acc[mi][ni] = __builtin_amdgcn_mfma_f32_16x16x32_bf16(af[mi], bfr[ni], acc[mi][ni], 0, 0, 0);
        }
        __syncthreads();
    }

    if (n0 < 2048) {
        // q/k: h-contiguous coalesced scatter
#pragma unroll
        for (int mi = 0; mi < 4; ++mi)
#pragma unroll
            for (int ni = 0; ni < 4; ++ni)
#pragma unroll
                for (int r = 0; r < 4; ++r) {
                    int m = m0 + wr * 64 + mi * 16 + g * 4 + r;
                    int c = n0 + wc * 64 + ni * 16 + c16;
                    int b = m >> 10, l = m & 1023;
                    int which = c >> 10, n = (c >> 6) & 15, h = c & 63;
                    unsigned short* dst = which == 0 ? q_buf : k_buf;
                    dst[(((size_t)b * 16 + n) * 1024 + l) * 64 + h] = f2bf(acc[mi][ni][r]);
                }
    } else {
        // v: LDS transpose, then 16B-coalesced stores to v_t
#pragma unroll
        for (int mi = 0; mi < 4; ++mi)
#pragma unroll
            for (int ni = 0; ni < 4; ++ni)
#pragma unroll
                for (int r = 0; r < 4; ++r) {
                    int l = wr * 64 + mi * 16 + g * 4 + r;
                    int cr = wc * 64 + ni * 16 + c16;
                    Sh[cr * 128 + (l ^ ((cr & 7) << 3))] = f2bf(acc[mi][ni][r]);
                }
        __syncthreads();
        const int b = m0 >> 10;
        const size_t rowbase = (size_t)(b * 1024 + (n0 - 2048)) * 1024 + (m0 & 1023);
#pragma unroll
        for (int c = 0; c < 8; ++c) {
            int chunk = c * 256 + tid;           // 2048 chunks of 8
            int cr = chunk >> 4, l0 = (chunk & 15) * 8;
            int lsw = l0 ^ ((cr & 7) << 3);
            u32x4 vv = *reinterpret_cast<const u32x4*>(&Sh[cr * 128 + lsw]);
            *reinterpret_cast<u32x4*>(v_t + rowbase + (size_t)cr * 1024 + l0) = vv;
        }
    }
}

// ---------------------------------------------------------------------------
// Merged q_proj / k_proj: grid (1, 1024); by<512 -> q, else k (+ kp_edge).
// ---------------------------------------------------------------------------
__global__ __launch_bounds__(256) void proj_kernel(
    const unsigned short* __restrict__ q_buf,
    const unsigned short* __restrict__ k_buf,
    const unsigned short* __restrict__ qe_bf,   // [128][64], row 127 = 0
    const unsigned short* __restrict__ ke_bf,
    unsigned short* __restrict__ q_proj,        // [65536][128]
    unsigned short* __restrict__ k_proj,
    unsigned short* __restrict__ kp_edge)       // [2][65536]
{
    __shared__ unsigned short As[128 * 64];
    __shared__ unsigned short Bs[128 * 64];
    const int by = blockIdx.y;
    const int which = by >> 9;                  // 0 = q, 1 = k
    const int m0 = (by & 511) * 128;
    const unsigned short* A  = which ? k_buf : q_buf;
    const unsigned short* Bt = which ? ke_bf : qe_bf;
    unsigned short* C0 = which ? k_proj : q_proj;

    const int tid = threadIdx.x;
    const int lane = tid & 63;
    const int w = tid >> 6;
    const int wr = w >> 1, wc = w & 1;
    const int g = lane >> 4, c16 = lane & 15;

    f32x4 acc[4][4];
#pragma unroll
    for (int i = 0; i < 4; ++i)
#pragma unroll
        for (int j = 0; j < 4; ++j) acc[i][j] = f32x4{0.f, 0.f, 0.f, 0.f};

#pragma unroll
    for (int c = 0; c < 4; ++c) {
        int chunk = c * 256 + tid;               // 1024 chunks of 16B
        int row = chunk >> 3, col = (chunk & 7) * 8;
        unsigned short* ldsA = &As[(c * 256 + w * 64) * 8];   // wave-uniform
        unsigned short* ldsB = &Bs[(c * 256 + w * 64) * 8];
        gl2lds16(A  + (size_t)(m0 + row) * 64 + col, ldsA);
        gl2lds16(Bt + (size_t)row * 64 + col, ldsB);
    }
    __syncthreads();
#pragma unroll
    for (int ks = 0; ks < 2; ++ks) {
        bf16x8 af[4], bfr[4];
#pragma unroll
        for (int mi = 0; mi < 4; ++mi)
            af[mi] = __builtin_bit_cast(bf16x8,
                *reinterpret_cast<const u32x4*>(&As[(wr * 64 + mi * 16 + c16) * 64 + ks * 32 + g * 8]));
#pragma unroll
        for (int ni = 0; ni < 4; ++ni)
            bfr[ni] = __builtin_bit_cast(bf16x8,
                *reinterpret_cast<const u32x4*>(&Bs[(wc * 64 + ni * 16 + c16) * 64 + ks * 32 + g * 8]));
#pragma unroll
        for (int mi = 0; mi < 4; ++mi)
#pragma unroll
            for (int ni = 0; ni < 4; ++ni)
                acc[mi][ni] = __builtin_amdgcn_mfma_f32_16x16x32_bf16(af[mi], bfr[ni], acc[mi][ni], 0, 0, 0);
    }

#pragma unroll
    for (int mi = 0; mi < 4; ++mi) {
#pragma unroll
        for (int ni = 0; ni < 4; ++ni) {
#pragma unroll
            for (int r = 0; r < 4; ++r) {
                int m = m0 + wr * 64 + mi * 16 + g * 4 + r;
                int c = wc * 64 + ni * 16 + c16;          // n0 = 0, N = 128
                float v = acc[mi][ni][r];
                C0[(size_t)m * 128 + c] = f2bf(v);
                if (which && (c == 0 || c == 126))
                    kp_edge[(size_t)(c ? 65536 : 0) + m] = f2bf(v);
            }
        }
    }
}

// ---------------------------------------------------------------------------
// Out-projection GEMM: [4096,1024] @ wo_bt^T -> fp32, 128x64 tiles.
// ---------------------------------------------------------------------------
__global__ __launch_bounds__(256) void gemm_n64_kernel(
    const unsigned short* __restrict__ A,       // [4096][1024] bf16
    const unsigned short* __restrict__ Bt,      // [1024][1024] bf16
    float* __restrict__ C)                      // [4096][1024] fp32
{
    __shared__ unsigned short As[128 * 64];
    __shared__ unsigned short Bs[64 * 64];
    const int m0 = blockIdx.y * 128;
    const int n0 = blockIdx.x * 64;
    const int tid = threadIdx.x;
    const int lane = tid & 63;
    const int w = tid >> 6;
    const int g = lane >> 4, c16 = lane & 15;

    f32x4 acc[2][4];
#pragma unroll
    for (int i = 0; i < 2; ++i)
#pragma unroll
        for (int j = 0; j < 4; ++j) acc[i][j] = f32x4{0.f, 0.f, 0.f, 0.f};

    for (int kt = 0; kt < 1024; kt += 64) {
#pragma unroll
        for (int c = 0; c < 4; ++c) {            // A: 1024 chunks of 16B
            int chunk = c * 256 + tid;
            int row = chunk >> 3, col = (chunk & 7) * 8;
            unsigned short* ldsA = &As[(c * 256 + w * 64) * 8];
            gl2lds16(A + (size_t)(m0 + row) * 1024 + kt + col, ldsA);
        }
#pragma unroll
        for (int c = 0; c < 2; ++c) {            // B: 512 chunks of 16B
            int chunk = c * 256 + tid;
            int row = chunk >> 3, col = (chunk & 7) * 8;
            unsigned short* ldsB = &Bs[(c * 256 + w * 64) * 8];
            gl2lds16(Bt + (size_t)(n0 + row) * 1024 + kt + col, ldsB);
        }
        __syncthreads();
#pragma unroll
        for (int ks = 0; ks < 2; ++ks) {
            bf16x8 af[2], bfr[4];
#pragma unroll
            for (int mi = 0; mi < 2; ++mi)
                af[mi] = __builtin_bit_cast(bf16x8,
                    *reinterpret_cast<const u32x4*>(&As[(w * 32 + mi * 16 + c16) * 64 + ks * 32 + g * 8]));
#pragma unroll
            for (int ni = 0; ni < 4; ++ni)
                bfr[ni] = __builtin_bit_cast(bf16x8,
                    *reinterpret_cast<const u32x4*>(&Bs[(ni * 16 + c16) * 64 + ks * 32 + g * 8]));
#pragma unroll
            for (int mi = 0; mi < 2; ++mi)
#pragma unroll
                for (int ni = 0; ni < 4; ++ni)
                    acc[mi][ni] = __builtin_amdgcn_mfma_f32_16x16x32_bf16(af[mi], bfr[ni], acc[mi][ni], 0, 0, 0);
        }
        __syncthreads();
    }

#pragma unroll
    for (int mi = 0; mi < 2; ++mi)
#pragma unroll
        for (int ni = 0; ni < 4; ++ni)
#pragma unroll
            for (int r = 0; r < 4; ++r) {
                int m = m0 + w * 32 + mi * 16 + g * 4 + r;
                int cc = n0 + ni * 16 + c16;
                C[(size_t)m * 1024 + cc] = acc[mi][ni][r];
            }
}

// ---------------------------------------------------------------------------
// Fused attention — ROUND-8 VERBATIM (validated 92 us steady-state).
// ---------------------------------------------------------------------------
#define ATTN_LDS_BYTES 54784

__global__ __launch_bounds__(512, 4) void attn_kernel(
    const unsigned short* __restrict__ q_buf,   // [B,N,L,H] bf16
    const unsigned short* __restrict__ k_buf,   // [B,N,L,H] bf16
    const unsigned short* __restrict__ v_t,     // [B,N,H,L] bf16
    const unsigned short* __restrict__ q_proj,  // [B,N,L,128] bf16
    const unsigned short* __restrict__ k_proj,  // [B,N,L,128] bf16
    const unsigned short* __restrict__ kp_edge, // [2][65536] bf16 (e=0,126)
    const unsigned short* __restrict__ ve_t,    // [64][128] bf16 (col 127 = 0)
    const int* __restrict__ mask,               // [B,1024]
    unsigned short* __restrict__ attn_out)      // [B,L,N,H] bf16
{
    extern __shared__ char smem[];
    unsigned short* Ks = (unsigned short*)smem;            // [64][72]
    unsigned short* Vt = (unsigned short*)(smem + 9216);   // [64][72]
    unsigned short* Ps = (unsigned short*)(smem + 18432);  // [128][72]
    unsigned short* kp = (unsigned short*)(smem + 36864);  // [64][136]
    float* mj   = (float*)(smem + 54272);                  // [64]
    float* kpej = (float*)(smem + 54528);                  // [64]
    unsigned short* veT = (unsigned short*)smem;           // [64][136] overlay
    unsigned short* peB = (unsigned short*)(smem + 17408); // [128][136] overlay
    float* lrow = (float*)(smem + 52224);                  // [128]

    const int id = blockIdx.x;
    const int bn = id & 63;                  // = b*16 + n (same XCD per group)
    const int ib = id >> 6;                  // i-block, 128 rows
    const int b = bn >> 4;
    const int i0 = ib * 128;
    const int tid = threadIdx.x;
    const int lane = tid & 63;
    const int w = tid >> 6;                  // wave 0..7, rows [w*16,w*16+16)
    const int g = lane >> 4, c16 = lane & 15;
    const int il = tid >> 2;                 // histogram row 0..127
    const int part = tid & 3;                // bins [part*32, part*32+32)

    const int jlo = 2 * ib - 1, jhi = 2 * ib + 2;   // kp-staging window

    // staging geometry
    const int sr = tid >> 3,  sc = (tid & 7) * 8;   // K/V: 512 x 16B chunks

    // Q fragments (A-row = c16), k-slot = ks*32 + 8g + slot
    bf16x8 qf[2];
    {
        const unsigned short* qrow = q_buf + ((size_t)bn * 1024 + i0 + w * 16 + c16) * 64;
        qf[0] = __builtin_bit_cast(bf16x8, *reinterpret_cast<const u32x4*>(qrow + g * 8));
        qf[1] = __builtin_bit_cast(bf16x8, *reinterpret_cast<const u32x4*>(qrow + 32 + g * 8));
    }
    // loop-invariant far-tile qp edge columns (global, 8 scalar loads)
    f32x4 qp0v, qp126v;
#pragma unroll
    for (int r = 0; r < 4; ++r) {
        size_t row = (size_t)bn * 1024 + i0 + w * 16 + g * 4 + r;
        qp0v[r]   = 0.125f * bf2f(q_proj[row * 128 + 0]);
        qp126v[r] = 0.125f * bf2f(q_proj[row * 128 + 126]);
    }

    float peR[32];
#pragma unroll
    for (int k = 0; k < 32; ++k) peR[k] = 0.f;
    float lreg = 0.f, acc0 = 0.f, acc126 = 0.f;
    f32x4 accO[4];
#pragma unroll
    for (int i = 0; i < 4; ++i) accO[i] = f32x4{0.f, 0.f, 0.f, 0.f};

    for (int jt = 0; jt < 16; ++jt) {
        const int j0 = jt * 64;
        const bool need_kp = (jt >= jlo) && (jt <= jhi);

        // ---- stage K, V^T (+ kp when near-union), mask, far edge bias ----
        {
            u32x4 kv = *reinterpret_cast<const u32x4*>(k_buf + ((size_t)bn * 1024 + j0 + sr) * 64 + sc);
            u32x4 vv = *reinterpret_cast<const u32x4*>(v_t + ((size_t)bn * 64 + sr) * 1024 + j0 + sc);
            *reinterpret_cast<u32x4*>(&Ks[sr * 72 + sc]) = kv;
            *reinterpret_cast<u32x4*>(&Vt[sr * 72 + sc]) = vv;
        }
        if (need_kp) {
#pragma unroll
            for (int c = 0; c < 2; ++c) {
                int chunk = tid + c * 512;        // 1024 chunks of 8 elems
                int row = chunk >> 4, col = (chunk & 15) * 8;
                u32x4 v = *reinterpret_cast<const u32x4*>(k_proj + ((size_t)bn * 1024 + j0 + row) * 128 + col);
                *reinterpret_cast<u32x4*>(&kp[row * 136 + col]) = v;
            }
        }
        if (tid < 64) {
            mj[tid] = mask[b * 1024 + j0 + tid] ? 1.f : 0.f;
            // far-plane: tiles left of the i-block use e=126, right use e=0
            kpej[tid] = 0.125f * bf2f(kp_edge[(size_t)(jt < 2 * ib ? 65536 : 0) + bn * 1024 + j0 + tid]);
        }
        __syncthreads();

        // ---- S = Q K^T ----
        f32x4 sacc[4];
#pragma unroll
        for (int nf = 0; nf < 4; ++nf) sacc[nf] = f32x4{0.f, 0.f, 0.f, 0.f};
#pragma unroll
        for (int ks = 0; ks < 2; ++ks)
#pragma unroll
            for (int nf = 0; nf < 4; ++nf) {
                bf16x8 kf = __builtin_bit_cast(bf16x8,
                    *reinterpret_cast<const u32x4*>(&Ks[(nf * 16 + c16) * 72 + ks * 32 + g * 8]));
                sacc[nf] = __builtin_amdgcn_mfma_f32_16x16x32_bf16(qf[ks], kf, sacc[nf], 0, 0, 0);
            }

        // ---- bias + exp + P store (wave-uniform near/far decision) ----
        const int dw = i0 + w * 16 - j0;
        if (dw < 126 && dw > -78) {
            // near: k-side gather from LDS kp, q-side gather from global
            const int d0 = i0 - j0 + 63;
            const unsigned short* qpg = q_proj + ((size_t)bn * 1024 + i0) * 128;
#pragma unroll
            for (int nf = 0; nf < 4; ++nf) {
                int j_l = nf * 16 + c16;
                float mfl = mj[j_l];
#pragma unroll
                for (int r = 0; r < 4; ++r) {
                    int i_l = w * 16 + g * 4 + r;
                    int e = d0 + i_l - j_l;
                    e = e < 0 ? 0 : (e > 126 ? 126 : e);
                    float s = sacc[nf][r] + bf2f(kp[j_l * 136 + e]) + bf2f(qpg[i_l * 128 + e]);
                    s *= 0.125f;
                    float p = (mfl > 0.f) ? __expf(s) : 0.f;
                    Ps[i_l * 72 + j_l] = f2bf(p);
                }
            }
        } else {
            const f32x4 qpc = (dw >= 126) ? qp126v : qp0v;
#pragma unroll
            for (int nf = 0; nf < 4; ++nf) {
                int j_l = nf * 16 + c16;
                float kv = kpej[j_l];
                float mfl = mj[j_l];
#pragma unroll
                for (int r = 0; r < 4; ++r) {
                    float s = sacc[nf][r] * 0.125f + kv + qpc[r];
                    float p = (mfl > 0.f) ? __expf(s) : 0.f;
                    Ps[(w * 16 + g * 4 + r) * 72 + j_l] = f2bf(p);
                }
            }
        }

        // ---- O += P @ V (Ps rows wave-private; lgkmcnt orders RAW) ----
#pragma unroll
        for (int ks = 0; ks < 2; ++ks) {
            bf16x8 pf = __builtin_bit_cast(bf16x8,
                *reinterpret_cast<const u32x4*>(&Ps[(w * 16 + c16) * 72 + ks * 32 + g * 8]));
#pragma unroll
            for (int nf2 = 0; nf2 < 4; ++nf2) {
                bf16x8 vf = __builtin_bit_cast(bf16x8,
                    *reinterpret_cast<const u32x4*>(&Vt[(nf2 * 16 + c16) * 72 + ks * 32 + g * 8]));
                accO[nf2] = __builtin_amdgcn_mfma_f32_16x16x32_bf16(pf, vf, accO[nf2], 0, 0, 0);
            }
        }

        // ---- pe histogram (register bins; per-row near/far) ----
        {
            bf16x8 s0 = __builtin_bit_cast(bf16x8,
                *reinterpret_cast<const u32x4*>(&Ps[il * 72 + part * 16]));
            bf16x8 s1 = __builtin_bit_cast(bf16x8,
                *reinterpret_cast<const u32x4*>(&Ps[il * 72 + part * 16 + 8]));
            float v[16];
#pragma unroll
            for (int m = 0; m < 8; ++m) { v[m] = (float)s0[m]; v[8 + m] = (float)s1[m]; }
            float rs = 0.f;
#pragma unroll
            for (int m = 0; m < 16; ++m) rs += v[m];
            rs += __shfl_xor(rs, 1);
            rs += __shfl_xor(rs, 2);
            lreg += rs;

            const int base = i0 + il - j0 + 63;   // jl for bin e is base - e
            if (base >= 189) {
                acc126 += rs;                     // every e >= 126
            } else if (base <= 0) {
                acc0 += rs;                       // every e <= 0
            } else {
                float b0 = 0.f, b126 = 0.f;
#pragma unroll
                for (int m = 0; m < 16; ++m) {
                    int jl = part * 16 + m;
                    if (jl >= base) b0 += v[m];
                    if (jl <= base - 126) b126 += v[m];
                }
                b0 += __shfl_xor(b0, 1);     b0 += __shfl_xor(b0, 2);
                b126 += __shfl_xor(b126, 1); b126 += __shfl_xor(b126, 2);
                if (part == 0) peR[0] += b0;
                if (part == 3) peR[30] += b126;
#pragma unroll
                for (int k = 0; k < 32; ++k) {
                    int e = part * 32 + k;
                    int jl = base - e;
                    if (e >= 1 && e <= 125 && jl >= 0 && jl < 64)
                        peR[k] += bf2f(Ps[il * 72 + jl]);
                }
            }
        }
        __syncthreads();                     // all waves done with Ks/Vt/kp
    }

    if (part == 0) peR[0] += acc0;
    if (part == 3) peR[30] += acc126;

    // ---- end phase: overlay veT/peB/lrow on dead Ks/Vt/Ps/kp ----
#pragma unroll
    for (int c = 0; c < 2; ++c) {
        int chunk = tid + c * 512;           // 1024 chunks of 8 elems = 64x128
        int h = chunk >> 4, col = (chunk & 15) * 8;
        u32x4 vv = *reinterpret_cast<const u32x4*>(ve_t + h * 128 + col);
        *reinterpret_cast<u32x4*>(&veT[h * 136 + col]) = vv;
    }
#pragma unroll
    for (int kk = 0; kk < 4; ++kk) {         // pe spill as bf16
        bf16x8 pk;
#pragma unroll
        for (int e2 = 0; e2 < 8; ++e2) pk[e2] = (__bf16)peR[kk * 8 + e2];
        *reinterpret_cast<u32x4*>(&peB[il * 136 + part * 32 + kk * 8]) =
            __builtin_bit_cast(u32x4, pk);
    }
    if (part == 0) lrow[il] = lreg;
    __syncthreads();

    // O += pe @ veT   (K = 128; col 127 zero on both sides)
#pragma unroll
    for (int ks = 0; ks < 4; ++ks) {
        bf16x8 pf = __builtin_bit_cast(bf16x8,
            *reinterpret_cast<const u32x4*>(&peB[(w * 16 + c16) * 136 + ks * 32 + g * 8]));
#pragma unroll
        for (int nf2 = 0; nf2 < 4; ++nf2) {
            bf16x8 vf = __builtin_bit_cast(bf16x8,
                *reinterpret_cast<const u32x4*>(&veT[(nf2 * 16 + c16) * 136 + ks * 32 + g * 8]));
            accO[nf2] = __builtin_amdgcn_mfma_f32_16x16x32_bf16(pf, vf, accO[nf2], 0, 0, 0);
        }
    }

    // epilogue: attn_out[b, i, n, h] = O / l
#pragma unroll
    for (int nf2 = 0; nf2 < 4; ++nf2) {
#pragma unroll
        for (int r = 0; r < 4; ++r) {
            int i_l = w * 16 + g * 4 + r;
            int h = nf2 * 16 + c16;
            float vv = accO[nf2][r] / lrow[i_l];
            attn_out[(((size_t)b * 1024 + i0 + i_l) * 16 + (bn & 15)) * 64 + h] = f2bf(vv);
        }
    }
}

// ---------------------------------------------------------------------------
extern "C" void kernel_launch(void* const* d_in, const int* in_sizes, int n_in,
                              void* d_out, int out_size, void* d_ws, size_t ws_size,
                              hipStream_t stream)
{
    const float* x  = (const float*)d_in[0];
    const int* mask = (const int*)d_in[1];
    const float* wq = (const float*)d_in[2];
    const float* wk = (const float*)d_in[3];
    const float* wv = (const float*)d_in[4];
    const float* wo = (const float*)d_in[5];
    const float* qe = (const float*)d_in[6];
    const float* ke = (const float*)d_in[7];
    const float* ve = (const float*)d_in[8];

    char* ws = (char*)d_ws;
    size_t off = 0;
    auto carve = [&](size_t bytes) -> char* {
        char* p = ws + off;
        off += (bytes + 255) & ~(size_t)255;
        return p;
    };
    unsigned short* x_bf    = (unsigned short*)carve(4096ull * 1024 * 2);   //  8 MB
    unsigned short* wqkv_bt = (unsigned short*)carve(3072ull * 1024 * 2);   //  6 MB
    unsigned short* wo_bt   = (unsigned short*)carve(1024ull * 1024 * 2);   //  2 MB
    unsigned short* qe_bf   = (unsigned short*)carve(128ull * 64 * 2);
    unsigned short* ke_bf   = (unsigned short*)carve(128ull * 64 * 2);
    unsigned short* ve_t    = (unsigned short*)carve(64ull * 128 * 2);
    unsigned short* q_buf   = (unsigned short*)carve(65536ull * 64 * 2);    //  8 MB
    unsigned short* k_buf   = (unsigned short*)carve(65536ull * 64 * 2);    //  8 MB
    unsigned short* v_t     = (unsigned short*)carve(65536ull * 64 * 2);    //  8 MB
    unsigned short* q_proj  = (unsigned short*)carve(65536ull * 128 * 2);   // 16 MB
    unsigned short* k_proj  = (unsigned short*)carve(65536ull * 128 * 2);   // 16 MB
    unsigned short* kp_edge = (unsigned short*)carve(2ull * 65536 * 2);     // 256 KB
    unsigned short* attn_o  = x_bf;   // alias: x_bf dead after QKV gemm
    (void)ws_size; (void)in_sizes; (void)n_in; (void)out_size;              // ~72.3 MB

    convert_kernel<<<1537, 256, 0, stream>>>(x, wq, wk, wv, wo, qe, ke, ve,
                                             x_bf, wqkv_bt, wo_bt, qe_bf, ke_bf, ve_t);

    // QKV: [4096,1024] @ [1024,3072]; v transposed via LDS (coalesced)
    gemm_qkv_kernel<<<dim3(24, 32), 256, 0, stream>>>(
        x_bf, wqkv_bt, q_buf, k_buf, v_t);

    // merged q_proj + k_proj (+ kp_edge): one 1024-block launch
    proj_kernel<<<dim3(1, 1024), 256, 0, stream>>>(
        q_buf, k_buf, qe_bf, ke_bf, q_proj, k_proj, kp_edge);

    // fused attention (round-8 verbatim; 8-wave blocks, 2 resident/CU)
    hipFuncSetAttribute((const void*)attn_kernel,
                        hipFuncAttributeMaxDynamicSharedMemorySize, ATTN_LDS_BYTES);
    attn_kernel<<<512, 512, ATTN_LDS_BYTES, stream>>>(
        q_buf, k_buf, v_t, q_proj, k_proj, kp_edge, ve_t, mask, attn_o);

    // output projection: 128x64 tiles, 512 blocks = 2/CU
    gemm_n64_kernel<<<dim3(16, 32), 256, 0, stream>>>(attn_o, wo_bt, (float*)d_out);
}

// Round 13
// 187.872 us; speedup vs baseline: 1.3484x; 1.0262x over previous
//
#include <hip/hip_runtime.h>

// ---------------------------------------------------------------------------
// MultiHeadAttention with clipped relative-position embeddings (q/k/v-side).
// B=4, L=1024, D=1024, N=16, H=64, E=64 (127 distinct distances).
//
// Pipeline:
//   0. convert_kernel : region-dispatched, all-coalesced (validated r12)
//   1. gemm_qkv       : QKV GEMM; q/k coalesced scatter; v -> v_t via LDS
//                       transpose, 16B-coalesced (validated r12)
//   2. proj_kernel    : q_proj + k_proj in one launch (+ kp_edge)
//   3. attn_kernel    : r8 structure + ASYNC global_load_lds staging:
//                       Ks/Vt linear [64][128B] DOUBLE-buffered, global src
//                       pre-swizzled (gch = (lane&7)^(row&7)), fragment reads
//                       XOR the chunk the same way (2-way banks = free).
//                       kp linear via DMA (gather is anti-diagonal -> 2-way).
//                       Prefetch jt+1 issues at top of jt's compute; drained
//                       by the single end-of-tile barrier. ZERO registers
//                       held across compute (r10's spill trap avoided).
//   4. gemm_n64       : out-proj 128x64 tiles -> fp32 d_out
// Workspace 72.3 MB (attn_o aliased onto dead x_bf; validated).
// ---------------------------------------------------------------------------

typedef __bf16 bf16x8 __attribute__((ext_vector_type(8)));
typedef float f32x4 __attribute__((ext_vector_type(4)));
typedef unsigned int u32x4 __attribute__((ext_vector_type(4)));
typedef unsigned short u16x4 __attribute__((ext_vector_type(4)));

__device__ __forceinline__ unsigned short f2bf(float f) {
    unsigned int u = __builtin_bit_cast(unsigned int, f);
    u += 0x7fffu + ((u >> 16) & 1u);          // RNE
    return (unsigned short)(u >> 16);
}
__device__ __forceinline__ float bf2f(unsigned short s) {
    unsigned int u = ((unsigned int)s) << 16;
    return __builtin_bit_cast(float, u);
}

// async global->LDS, 16 bytes per lane; LDS dest must be wave-uniform base
__device__ __forceinline__ void gl2lds16(const unsigned short* g, unsigned short* l) {
    __builtin_amdgcn_global_load_lds(
        (const __attribute__((address_space(1))) unsigned int*)g,
        (__attribute__((address_space(3))) unsigned int*)l, 16, 0, 0);
}

// ---------------------------------------------------------------------------
// Convert / relayout kernel — all regions coalesced.
// ---------------------------------------------------------------------------
__global__ __launch_bounds__(256) void convert_kernel(
    const float* __restrict__ x,
    const float* __restrict__ wq,
    const float* __restrict__ wk,
    const float* __restrict__ wv,
    const float* __restrict__ wo,
    const float* __restrict__ qe,
    const float* __restrict__ ke,
    const float* __restrict__ ve,
    unsigned short* __restrict__ x_bf,
    unsigned short* __restrict__ wqkv_bt,
    unsigned short* __restrict__ wo_bt,
    unsigned short* __restrict__ qe_bf,
    unsigned short* __restrict__ ke_bf,
    unsigned short* __restrict__ ve_t)
{
    __shared__ unsigned short T[64 * 72];
    const int bid = blockIdx.x;
    const int tid = threadIdx.x;

    if (bid < 512) {
        const float* src = x + (size_t)bid * 8192;
        unsigned short* dst = x_bf + (size_t)bid * 8192;
#pragma unroll
        for (int c = 0; c < 8; ++c) {
            int idx = c * 1024 + tid * 4;
            f32x4 v = *reinterpret_cast<const f32x4*>(src + idx);
            u16x4 o = u16x4{f2bf(v[0]), f2bf(v[1]), f2bf(v[2]), f2bf(v[3])};
            *reinterpret_cast<u16x4*>(dst + idx) = o;
        }
    } else if (bid < 1280) {
        int t = bid - 512;
        int which = t >> 8, n = (t >> 4) & 15, dt = t & 15;
        const float* w = which == 0 ? wq : which == 1 ? wk : wv;
        const float* src = w + ((size_t)n * 1024 + dt * 64) * 64;   // [dd][hh]
#pragma unroll
        for (int c = 0; c < 4; ++c) {
            int chunk = c * 256 + tid;             // 1024 chunks of 4 f32
            int dd = chunk >> 4, hh = (chunk & 15) * 4;
            f32x4 v = *reinterpret_cast<const f32x4*>(src + dd * 64 + hh);
#pragma unroll
            for (int j = 0; j < 4; ++j) T[(hh + j) * 72 + dd] = f2bf(v[j]);
        }
        __syncthreads();
        unsigned short* dstb = wqkv_bt + ((size_t)(which * 1024 + n * 64)) * 1024 + dt * 64;
#pragma unroll
        for (int c = 0; c < 2; ++c) {
            int chunk = c * 256 + tid;             // 512 chunks of 8
            int h = chunk >> 3, d8 = (chunk & 7) * 8;
            u32x4 v = *reinterpret_cast<const u32x4*>(&T[h * 72 + d8]);
            *reinterpret_cast<u32x4*>(dstb + (size_t)h * 1024 + d8) = v;
        }
    } else if (bid < 1536) {
        int t = bid - 1280;
        int n = t >> 4, mt = t & 15;
        const float* src = wo + (size_t)n * 64 * 1024 + mt * 64;    // [hh][mm]
#pragma unroll
        for (int c = 0; c < 4; ++c) {
            int chunk = c * 256 + tid;             // 1024 chunks of 4 f32
            int hh = chunk >> 4, mm = (chunk & 15) * 4;
            f32x4 v = *reinterpret_cast<const f32x4*>(src + (size_t)hh * 1024 + mm);
#pragma unroll
            for (int j = 0; j < 4; ++j) T[(mm + j) * 72 + hh] = f2bf(v[j]);
        }
        __syncthreads();
        unsigned short* dstb = wo_bt + (size_t)(mt * 64) * 1024 + n * 64;
#pragma unroll
        for (int c = 0; c < 2; ++c) {
            int chunk = c * 256 + tid;             // 512 chunks of 8
            int m = chunk >> 3, h8 = (chunk & 7) * 8;
            u32x4 v = *reinterpret_cast<const u32x4*>(&T[m * 72 + h8]);
            *reinterpret_cast<u32x4*>(dstb + (size_t)m * 1024 + h8) = v;
        }
    } else {
        for (int i = tid; i < 8192; i += 256) {
            int e = i >> 6;
            qe_bf[i] = (e < 127) ? f2bf(qe[i]) : 0;
            ke_bf[i] = (e < 127) ? f2bf(ke[i]) : 0;
            int h = i >> 7, e2 = i & 127;
            ve_t[i] = (e2 < 127) ? f2bf(ve[e2 * 64 + h]) : 0;
        }
    }
}

// ---------------------------------------------------------------------------
// QKV GEMM (validated r12): q/k coalesced scatter; v via LDS transpose.
// ---------------------------------------------------------------------------
__global__ __launch_bounds__(256) void gemm_qkv_kernel(
    const unsigned short* __restrict__ A,
    const unsigned short* __restrict__ Bt,
    unsigned short* __restrict__ q_buf,
    unsigned short* __restrict__ k_buf,
    unsigned short* __restrict__ v_t)
{
    __shared__ unsigned short Sh[2 * 128 * 64];    // As | Bs; reused as T[128][128]
    unsigned short* As = Sh;
    unsigned short* Bs = Sh + 8192;
    const int m0 = blockIdx.y * 128;
    const int n0 = blockIdx.x * 128;
    const int tid = threadIdx.x;
    const int lane = tid & 63;
    const int w = tid >> 6;
    const int wr = w >> 1, wc = w & 1;
    const int g = lane >> 4, c16 = lane & 15;

    f32x4 acc[4][4];
#pragma unroll
    for (int i = 0; i < 4; ++i)
#pragma unroll
        for (int j = 0; j < 4; ++j) acc[i][j] = f32x4{0.f, 0.f, 0.f, 0.f};

    for (int kt = 0; kt < 1024; kt += 64) {
#pragma unroll
        for (int c = 0; c < 4; ++c) {
            int chunk = c * 256 + tid;           // 1024 chunks of 16B
            int row = chunk >> 3, col = (chunk & 7) * 8;
            unsigned short* ldsA = &As[(c * 256 + w * 64) * 8];   // wave-uniform
            unsigned short* ldsB = &Bs[(c * 256 + w * 64) * 8];
            gl2lds16(A  + (size_t)(m0 + row) * 1024 + kt + col, ldsA);
            gl2lds16(Bt + (size_t)(n0 + row) * 1024 + kt + col, ldsB);
        }
        __syncthreads();
#pragma unroll
        for (int ks = 0; ks < 2; ++ks) {
            bf16x8 af[4], bfr[4];
#pragma unroll
            for (int mi = 0; mi < 4; ++mi)
                af[mi] = __builtin_bit_cast(bf16x8,
                    *reinterpret_cast<const u32x4*>(&As[(wr * 64 + mi * 16 + c16) * 64 + ks * 32 + g * 8]));
#pragma unroll
            for (int ni = 0; ni < 4; ++ni)
                bfr[ni] = __builtin_bit_cast(bf16x8,
                    *reinterpret_cast<const u32x4*>(&Bs[(wc * 64 + ni * 16 + c16) * 64 + ks * 32 + g * 8]));
#pragma unroll
            for (int mi = 0; mi < 4; ++mi)
#pragma unroll
                for (int ni = 0; ni < 4; ++ni)
                    acc[mi][ni] = __builtin_amdgcn_mfma_f32_16x16x32_bf16(af[mi], bfr[ni], acc[mi][ni], 0, 0, 0);
        }
        __syncthreads();
    }

    if (n0 < 2048) {
#pragma unroll
        for (int mi = 0; mi < 4; ++mi)
#pragma unroll
            for (int ni = 0; ni < 4; ++ni)
#pragma unroll
                for (int r = 0; r < 4; ++r) {
                    int m = m0 + wr * 64 + mi * 16 + g * 4 + r;
                    int c = n0 + wc * 64 + ni * 16 + c16;
                    int b = m >> 10, l = m & 1023;
                    int which = c >> 10, n = (c >> 6) & 15, h = c & 63;
                    unsigned short* dst = which == 0 ? q_buf : k_buf;
                    dst[(((size_t)b * 16 + n) * 1024 + l) * 64 + h] = f2bf(acc[mi][ni][r]);
                }
    } else {
#pragma unroll
        for (int mi = 0; mi < 4; ++mi)
#pragma unroll
            for (int ni = 0; ni < 4; ++ni)
#pragma unroll
                for (int r = 0; r < 4; ++r) {
                    int l = wr * 64 + mi * 16 + g * 4 + r;
                    int cr = wc * 64 + ni * 16 + c16;
                    Sh[cr * 128 + (l ^ ((cr & 7) << 3))] = f2bf(acc[mi][ni][r]);
                }
        __syncthreads();
        const int b = m0 >> 10;
        const size_t rowbase = (size_t)(b * 1024 + (n0 - 2048)) * 1024 + (m0 & 1023);
#pragma unroll
        for (int c = 0; c < 8; ++c) {
            int chunk = c * 256 + tid;           // 2048 chunks of 8
            int cr = chunk >> 4, l0 = (chunk & 15) * 8;
            int lsw = l0 ^ ((cr & 7) << 3);
            u32x4 vv = *reinterpret_cast<const u32x4*>(&Sh[cr * 128 + lsw]);
            *reinterpret_cast<u32x4*>(v_t + rowbase + (size_t)cr * 1024 + l0) = vv;
        }
    }
}

// ---------------------------------------------------------------------------
// Merged q_proj / k_proj: grid (1, 1024); by<512 -> q, else k (+ kp_edge).
// ---------------------------------------------------------------------------
__global__ __launch_bounds__(256) void proj_kernel(
    const unsigned short* __restrict__ q_buf,
    const unsigned short* __restrict__ k_buf,
    const unsigned short* __restrict__ qe_bf,   // [128][64], row 127 = 0
    const unsigned short* __restrict__ ke_bf,
    unsigned short* __restrict__ q_proj,        // [65536][128]
    unsigned short* __restrict__ k_proj,
    unsigned short* __restrict__ kp_edge)       // [2][65536]
{
    __shared__ unsigned short As[128 * 64];
    __shared__ unsigned short Bs[128 * 64];
    const int by = blockIdx.y;
    const int which = by >> 9;                  // 0 = q, 1 = k
    const int m0 = (by & 511) * 128;
    const unsigned short* A  = which ? k_buf : q_buf;
    const unsigned short* Bt = which ? ke_bf : qe_bf;
    unsigned short* C0 = which ? k_proj : q_proj;

    const int tid = threadIdx.x;
    const int lane = tid & 63;
    const int w = tid >> 6;
    const int wr = w >> 1, wc = w & 1;
    const int g = lane >> 4, c16 = lane & 15;

    f32x4 acc[4][4];
#pragma unroll
    for (int i = 0; i < 4; ++i)
#pragma unroll
        for (int j = 0; j < 4; ++j) acc[i][j] = f32x4{0.f, 0.f, 0.f, 0.f};

#pragma unroll
    for (int c = 0; c < 4; ++c) {
        int chunk = c * 256 + tid;               // 1024 chunks of 16B
        int row = chunk >> 3, col = (chunk & 7) * 8;
        unsigned short* ldsA = &As[(c * 256 + w * 64) * 8];   // wave-uniform
        unsigned short* ldsB = &Bs[(c * 256 + w * 64) * 8];
        gl2lds16(A  + (size_t)(m0 + row) * 64 + col, ldsA);
        gl2lds16(Bt + (size_t)row * 64 + col, ldsB);
    }
    __syncthreads();
#pragma unroll
    for (int ks = 0; ks < 2; ++ks) {
        bf16x8 af[4], bfr[4];
#pragma unroll
        for (int mi = 0; mi < 4; ++mi)
            af[mi] = __builtin_bit_cast(bf16x8,
                *reinterpret_cast<const u32x4*>(&As[(wr * 64 + mi * 16 + c16) * 64 + ks * 32 + g * 8]));
#pragma unroll
        for (int ni = 0; ni < 4; ++ni)
            bfr[ni] = __builtin_bit_cast(bf16x8,
                *reinterpret_cast<const u32x4*>(&Bs[(wc * 64 + ni * 16 + c16) * 64 + ks * 32 + g * 8]));
#pragma unroll
        for (int mi = 0; mi < 4; ++mi)
#pragma unroll
            for (int ni = 0; ni < 4; ++ni)
                acc[mi][ni] = __builtin_amdgcn_mfma_f32_16x16x32_bf16(af[mi], bfr[ni], acc[mi][ni], 0, 0, 0);
    }

#pragma unroll
    for (int mi = 0; mi < 4; ++mi) {
#pragma unroll
        for (int ni = 0; ni < 4; ++ni) {
#pragma unroll
            for (int r = 0; r < 4; ++r) {
                int m = m0 + wr * 64 + mi * 16 + g * 4 + r;
                int c = wc * 64 + ni * 16 + c16;          // n0 = 0, N = 128
                float v = acc[mi][ni][r];
                C0[(size_t)m * 128 + c] = f2bf(v);
                if (which && (c == 0 || c == 126))
                    kp_edge[(size_t)(c ? 65536 : 0) + m] = f2bf(v);
            }
        }
    }
}

// ---------------------------------------------------------------------------
// Out-projection GEMM: [4096,1024] @ wo_bt^T -> fp32, 128x64 tiles.
// ---------------------------------------------------------------------------
__global__ __launch_bounds__(256) void gemm_n64_kernel(
    const unsigned short* __restrict__ A,       // [4096][1024] bf16
    const unsigned short* __restrict__ Bt,      // [1024][1024] bf16
    float* __restrict__ C)                      // [4096][1024] fp32
{
    __shared__ unsigned short As[128 * 64];
    __shared__ unsigned short Bs[64 * 64];
    const int m0 = blockIdx.y * 128;
    const int n0 = blockIdx.x * 64;
    const int tid = threadIdx.x;
    const int lane = tid & 63;
    const int w = tid >> 6;
    const int g = lane >> 4, c16 = lane & 15;

    f32x4 acc[2][4];
#pragma unroll
    for (int i = 0; i < 2; ++i)
#pragma unroll
        for (int j = 0; j < 4; ++j) acc[i][j] = f32x4{0.f, 0.f, 0.f, 0.f};

    for (int kt = 0; kt < 1024; kt += 64) {
#pragma unroll
        for (int c = 0; c < 4; ++c) {            // A: 1024 chunks of 16B
            int chunk = c * 256 + tid;
            int row = chunk >> 3, col = (chunk & 7) * 8;
            unsigned short* ldsA = &As[(c * 256 + w * 64) * 8];
            gl2lds16(A + (size_t)(m0 + row) * 1024 + kt + col, ldsA);
        }
#pragma unroll
        for (int c = 0; c < 2; ++c) {            // B: 512 chunks of 16B
            int chunk = c * 256 + tid;
            int row = chunk >> 3, col = (chunk & 7) * 8;
            unsigned short* ldsB = &Bs[(c * 256 + w * 64) * 8];
            gl2lds16(Bt + (size_t)(n0 + row) * 1024 + kt + col, ldsB);
        }
        __syncthreads();
#pragma unroll
        for (int ks = 0; ks < 2; ++ks) {
            bf16x8 af[2], bfr[4];
#pragma unroll
            for (int mi = 0; mi < 2; ++mi)
                af[mi] = __builtin_bit_cast(bf16x8,
                    *reinterpret_cast<const u32x4*>(&As[(w * 32 + mi * 16 + c16) * 64 + ks * 32 + g * 8]));
#pragma unroll
            for (int ni = 0; ni < 4; ++ni)
                bfr[ni] = __builtin_bit_cast(bf16x8,
                    *reinterpret_cast<const u32x4*>(&Bs[(ni * 16 + c16) * 64 + ks * 32 + g * 8]));
#pragma unroll
            for (int mi = 0; mi < 2; ++mi)
#pragma unroll
                for (int ni = 0; ni < 4; ++ni)
                    acc[mi][ni] = __builtin_amdgcn_mfma_f32_16x16x32_bf16(af[mi], bfr[ni], acc[mi][ni], 0, 0, 0);
        }
        __syncthreads();
    }

#pragma unroll
    for (int mi = 0; mi < 2; ++mi)
#pragma unroll
        for (int ni = 0; ni < 4; ++ni)
#pragma unroll
            for (int r = 0; r < 4; ++r) {
                int m = m0 + w * 32 + mi * 16 + g * 4 + r;
                int cc = n0 + ni * 16 + c16;
                C[(size_t)m * 1024 + cc] = acc[mi][ni][r];
            }
}

// ---------------------------------------------------------------------------
// Fused attention. 512 threads (8 waves), QBLK=128, KVBLK=64, grid 512.
// ASYNC staging via global_load_lds (zero prefetch registers):
//  LDS: KsL[2][64][128B] @0/@8192 (linear, src-swizzled)
//       VtL[2][64][128B] @16384/@24576
//       Ps  [128][72]    @32768  (18432 B, reg-written, unchanged)
//       kp  [64][128]    @51200  (16384 B, linear via DMA; bias gather is
//                                 anti-diagonal -> 2-way banks, free)
//       mjI [2][64] int  @67584  (512 B)   kpeU[2][64] u16 @68096 (256 B)
//  -> 68352 B, 2 blocks/CU. End overlay: veT@0, peB@17408, lrow@52224.
// Swizzle: LDS chunk c of row r holds global chunk c^(r&7); DMA lane computes
// gchunk=(lane&7)^(row&7); fragment reads XOR chunk with (c16&7) -> 2-way.
// Steady state 1 barrier/tile; kp-window tiles (4/16) take one extra.
// ---------------------------------------------------------------------------
#define ATTN_LDS_BYTES 68352

__global__ __launch_bounds__(512, 4) void attn_kernel(
    const unsigned short* __restrict__ q_buf,   // [B,N,L,H] bf16
    const unsigned short* __restrict__ k_buf,   // [B,N,L,H] bf16
    const unsigned short* __restrict__ v_t,     // [B,N,H,L] bf16
    const unsigned short* __restrict__ q_proj,  // [B,N,L,128] bf16
    const unsigned short* __restrict__ k_proj,  // [B,N,L,128] bf16
    const unsigned short* __restrict__ kp_edge, // [2][65536] bf16 (e=0,126)
    const unsigned short* __restrict__ ve_t,    // [64][128] bf16 (col 127 = 0)
    const int* __restrict__ mask,               // [B,1024]
    unsigned short* __restrict__ attn_out)      // [B,L,N,H] bf16
{
    extern __shared__ char smem[];
    unsigned short* Ps   = (unsigned short*)(smem + 32768); // [128][72]
    unsigned short* kp   = (unsigned short*)(smem + 51200); // [64][128]
    int*            mjI  = (int*)(smem + 67584);            // [2][64]
    unsigned short* kpeU = (unsigned short*)(smem + 68096); // [2][64]
    unsigned short* veT = (unsigned short*)smem;            // [64][136] overlay
    unsigned short* peB = (unsigned short*)(smem + 17408);  // [128][136] overlay
    float* lrow = (float*)(smem + 52224);                   // [128]

    const int id = blockIdx.x;
    const int bn = id & 63;                  // = b*16 + n (same XCD per group)
    const int ib = id >> 6;                  // i-block, 128 rows
    const int b = bn >> 4;
    const int i0 = ib * 128;
    const int tid = threadIdx.x;
    const int lane = tid & 63;
    const int w = tid >> 6;                  // wave 0..7, rows [w*16,w*16+16)
    const int g = lane >> 4, c16 = lane & 15;
    const int il = tid >> 2;                 // histogram row 0..127
    const int part = tid & 3;                // bins [part*32, part*32+32)
    const int swz = c16 & 7;                 // fragment-read chunk XOR

    const int jlo = 2 * ib - 1, jhi = 2 * ib + 2;   // kp window

    // DMA geometry: wave w covers rows [w*8, w*8+8) of a [64][128B] tile
    const int srow = w * 8 + (lane >> 3);
    const int gch  = (lane & 7) ^ (srow & 7);       // pre-swizzled chunk

    auto issue_kv = [&](int j0n, int nxt) {
        gl2lds16(k_buf + ((size_t)bn * 1024 + j0n + srow) * 64 + gch * 8,
                 (unsigned short*)(smem + nxt * 8192) + w * 512);
        gl2lds16(v_t + ((size_t)bn * 64 + srow) * 1024 + j0n + gch * 8,
                 (unsigned short*)(smem + 16384 + nxt * 8192) + w * 512);
    };
    auto stage_scalar = [&](int jtn, int nxt) {     // waves 0/1, plain ld+st
        int j0n = jtn * 64;
        if (w == 0) mjI[nxt * 64 + lane] = mask[b * 1024 + j0n + lane];
        if (w == 1) kpeU[nxt * 64 + lane] =
            kp_edge[(size_t)(jtn < 2 * ib ? 65536 : 0) + bn * 1024 + j0n + lane];
    };
    auto issue_kp = [&](int jtn) {                  // [64][128] linear, 16 KB
        int j0n = jtn * 64;
#pragma unroll
        for (int c = 0; c < 2; ++c) {
            int chunk = w * 128 + c * 64 + lane;
            int row = chunk >> 4, col8 = chunk & 15;
            gl2lds16(k_proj + ((size_t)bn * 1024 + j0n + row) * 128 + col8 * 8,
                     kp + (w * 128 + c * 64) * 8);
        }
    };

    // prologue: tile 0 in flight
    issue_kv(0, 0);
    stage_scalar(0, 0);
    if (0 >= jlo && 0 <= jhi) issue_kp(0);

    // Q fragments + loop-invariant qp edge columns (overlap tile-0 latency)
    bf16x8 qf[2];
    {
        const unsigned short* qrow = q_buf + ((size_t)bn * 1024 + i0 + w * 16 + c16) * 64;
        qf[0] = __builtin_bit_cast(bf16x8, *reinterpret_cast<const u32x4*>(qrow + g * 8));
        qf[1] = __builtin_bit_cast(bf16x8, *reinterpret_cast<const u32x4*>(qrow + 32 + g * 8));
    }
    f32x4 qp0v, qp126v;
#pragma unroll
    for (int r = 0; r < 4; ++r) {
        size_t row = (size_t)bn * 1024 + i0 + w * 16 + g * 4 + r;
        qp0v[r]   = 0.125f * bf2f(q_proj[row * 128 + 0]);
        qp126v[r] = 0.125f * bf2f(q_proj[row * 128 + 126]);
    }

    float peR[32];
#pragma unroll
    for (int k = 0; k < 32; ++k) peR[k] = 0.f;
    float lreg = 0.f, acc0 = 0.f, acc126 = 0.f;
    f32x4 accO[4];
#pragma unroll
    for (int i = 0; i < 4; ++i) accO[i] = f32x4{0.f, 0.f, 0.f, 0.f};

    __syncthreads();                          // tile 0 resident

    for (int jt = 0; jt < 16; ++jt) {
        const int cur = jt & 1;
        const int j0 = jt * 64;
        const unsigned short* Ksc = (const unsigned short*)(smem + cur * 8192);
        const unsigned short* Vtc = (const unsigned short*)(smem + 16384 + cur * 8192);

        if (jt < 15) {                        // async prefetch of jt+1
            issue_kv(j0 + 64, cur ^ 1);
            stage_scalar(jt + 1, cur ^ 1);
        }

        // ---- S = Q K^T (swizzled fragment reads) ----
        f32x4 sacc[4];
#pragma unroll
        for (int nf = 0; nf < 4; ++nf) sacc[nf] = f32x4{0.f, 0.f, 0.f, 0.f};
#pragma unroll
        for (int ks = 0; ks < 2; ++ks)
#pragma unroll
            for (int nf = 0; nf < 4; ++nf) {
                bf16x8 kf = __builtin_bit_cast(bf16x8,
                    *reinterpret_cast<const u32x4*>(&Ksc[(nf * 16 + c16) * 64 + ((ks * 4 + g) ^ swz) * 8]));
                sacc[nf] = __builtin_amdgcn_mfma_f32_16x16x32_bf16(qf[ks], kf, sacc[nf], 0, 0, 0);
            }

        // ---- bias + exp + P store (wave-uniform near/far decision) ----
        const int dw = i0 + w * 16 - j0;
        if (dw < 126 && dw > -78) {
            const int d0 = i0 - j0 + 63;
            const unsigned short* qpg = q_proj + ((size_t)bn * 1024 + i0) * 128;
#pragma unroll
            for (int nf = 0; nf < 4; ++nf) {
                int j_l = nf * 16 + c16;
                float mfl = mjI[cur * 64 + j_l] ? 1.f : 0.f;
#pragma unroll
                for (int r = 0; r < 4; ++r) {
                    int i_l = w * 16 + g * 4 + r;
                    int e = d0 + i_l - j_l;
                    e = e < 0 ? 0 : (e > 126 ? 126 : e);
                    float s = sacc[nf][r] + bf2f(kp[j_l * 128 + e]) + bf2f(qpg[i_l * 128 + e]);
                    s *= 0.125f;
                    float p = (mfl > 0.f) ? __expf(s) : 0.f;
                    Ps[i_l * 72 + j_l] = f2bf(p);
                }
            }
        } else {
            const f32x4 qpc = (dw >= 126) ? qp126v : qp0v;
#pragma unroll
            for (int nf = 0; nf < 4; ++nf) {
                int j_l = nf * 16 + c16;
                float kv = 0.125f * bf2f(kpeU[cur * 64 + j_l]);
                float mfl = mjI[cur * 64 + j_l] ? 1.f : 0.f;
#pragma unroll
                for (int r = 0; r < 4; ++r) {
                    float s = sacc[nf][r] * 0.125f + kv + qpc[r];
                    float p = (mfl > 0.f) ? __expf(s) : 0.f;
                    Ps[(w * 16 + g * 4 + r) * 72 + j_l] = f2bf(p);
                }
            }
        }

        // ---- O += P @ V (Ps rows wave-private; lgkmcnt orders RAW) ----
#pragma unroll
        for (int ks = 0; ks < 2; ++ks) {
            bf16x8 pf = __builtin_bit_cast(bf16x8,
                *reinterpret_cast<const u32x4*>(&Ps[(w * 16 + c16) * 72 + ks * 32 + g * 8]));
#pragma unroll
            for (int nf2 = 0; nf2 < 4; ++nf2) {
                bf16x8 vf = __builtin_bit_cast(bf16x8,
                    *reinterpret_cast<const u32x4*>(&Vtc[(nf2 * 16 + c16) * 64 + ((ks * 4 + g) ^ swz) * 8]));
                accO[nf2] = __builtin_amdgcn_mfma_f32_16x16x32_bf16(pf, vf, accO[nf2], 0, 0, 0);
            }
        }

        // ---- pe histogram (register bins; per-row near/far) ----
        {
            bf16x8 s0 = __builtin_bit_cast(bf16x8,
                *reinterpret_cast<const u32x4*>(&Ps[il * 72 + part * 16]));
            bf16x8 s1 = __builtin_bit_cast(bf16x8,
                *reinterpret_cast<const u32x4*>(&Ps[il * 72 + part * 16 + 8]));
            float v[16];
#pragma unroll
            for (int m = 0; m < 8; ++m) { v[m] = (float)s0[m]; v[8 + m] = (float)s1[m]; }
            float rs = 0.f;
#pragma unroll
            for (int m = 0; m < 16; ++m) rs += v[m];
            rs += __shfl_xor(rs, 1);
            rs += __shfl_xor(rs, 2);
            lreg += rs;

            const int base = i0 + il - j0 + 63;   // jl for bin e is base - e
            if (base >= 189) {
                acc126 += rs;
            } else if (base <= 0) {
                acc0 += rs;
            } else {
                float b0 = 0.f, b126 = 0.f;
#pragma unroll
                for (int m = 0; m < 16; ++m) {
                    int jl = part * 16 + m;
                    if (jl >= base) b0 += v[m];
                    if (jl <= base - 126) b126 += v[m];
                }
                b0 += __shfl_xor(b0, 1);     b0 += __shfl_xor(b0, 2);
                b126 += __shfl_xor(b126, 1); b126 += __shfl_xor(b126, 2);
                if (part == 0) peR[0] += b0;
                if (part == 3) peR[30] += b126;
#pragma unroll
                for (int k = 0; k < 32; ++k) {
                    int e = part * 32 + k;
                    int jl = base - e;
                    if (e >= 1 && e <= 125 && jl >= 0 && jl < 64)
                        peR[k] += bf2f(Ps[il * 72 + jl]);
                }
            }
        }

        // ---- end of tile: one barrier; kp-window tiles take an extra ----
        const bool kpn = (jt < 15) && (jt + 1 >= jlo) && (jt + 1 <= jhi);
        __syncthreads();                     // drains prefetch; frees kp/Ps
        if (kpn) {
            issue_kp(jt + 1);                // kp readers (tile jt) done
            __syncthreads();                 // kp(jt+1) resident
        }
    }

    if (part == 0) peR[0] += acc0;
    if (part == 3) peR[30] += acc126;

    // ---- end phase: overlay veT/peB/lrow on dead staging ----
#pragma unroll
    for (int c = 0; c < 2; ++c) {
        int chunk = tid + c * 512;           // 1024 chunks of 8 elems = 64x128
        int h = chunk >> 4, col = (chunk & 15) * 8;
        u32x4 vv = *reinterpret_cast<const u32x4*>(ve_t + h * 128 + col);
        *reinterpret_cast<u32x4*>(&veT[h * 136 + col]) = vv;
    }
#pragma unroll
    for (int kk = 0; kk < 4; ++kk) {         // pe spill as bf16
        bf16x8 pk;
#pragma unroll
        for (int e2 = 0; e2 < 8; ++e2) pk[e2] = (__bf16)peR[kk * 8 + e2];
        *reinterpret_cast<u32x4*>(&peB[il * 136 + part * 32 + kk * 8]) =
            __builtin_bit_cast(u32x4, pk);
    }
    if (part == 0) lrow[il] = lreg;
    __syncthreads();

    // O += pe @ veT   (K = 128; col 127 zero on both sides)
#pragma unroll
    for (int ks = 0; ks < 4; ++ks) {
        bf16x8 pf = __builtin_bit_cast(bf16x8,
            *reinterpret_cast<const u32x4*>(&peB[(w * 16 + c16) * 136 + ks * 32 + g * 8]));
#pragma unroll
        for (int nf2 = 0; nf2 < 4; ++nf2) {
            bf16x8 vf = __builtin_bit_cast(bf16x8,
                *reinterpret_cast<const u32x4*>(&veT[(nf2 * 16 + c16) * 136 + ks * 32 + g * 8]));
            accO[nf2] = __builtin_amdgcn_mfma_f32_16x16x32_bf16(pf, vf, accO[nf2], 0, 0, 0);
        }
    }

    // epilogue: attn_out[b, i, n, h] = O / l
#pragma unroll
    for (int nf2 = 0; nf2 < 4; ++nf2) {
#pragma unroll
        for (int r = 0; r < 4; ++r) {
            int i_l = w * 16 + g * 4 + r;
            int h = nf2 * 16 + c16;
            float vv = accO[nf2][r] / lrow[i_l];
            attn_out[(((size_t)b * 1024 + i0 + i_l) * 16 + (bn & 15)) * 64 + h] = f2bf(vv);
        }
    }
}

// ---------------------------------------------------------------------------
extern "C" void kernel_launch(void* const* d_in, const int* in_sizes, int n_in,
                              void* d_out, int out_size, void* d_ws, size_t ws_size,
                              hipStream_t stream)
{
    const float* x  = (const float*)d_in[0];
    const int* mask = (const int*)d_in[1];
    const float* wq = (const float*)d_in[2];
    const float* wk = (const float*)d_in[3];
    const float* wv = (const float*)d_in[4];
    const float* wo = (const float*)d_in[5];
    const float* qe = (const float*)d_in[6];
    const float* ke = (const float*)d_in[7];
    const float* ve = (const float*)d_in[8];

    char* ws = (char*)d_ws;
    size_t off = 0;
    auto carve = [&](size_t bytes) -> char* {
        char* p = ws + off;
        off += (bytes + 255) & ~(size_t)255;
        return p;
    };
    unsigned short* x_bf    = (unsigned short*)carve(4096ull * 1024 * 2);   //  8 MB
    unsigned short* wqkv_bt = (unsigned short*)carve(3072ull * 1024 * 2);   //  6 MB
    unsigned short* wo_bt   = (unsigned short*)carve(1024ull * 1024 * 2);   //  2 MB
    unsigned short* qe_bf   = (unsigned short*)carve(128ull * 64 * 2);
    unsigned short* ke_bf   = (unsigned short*)carve(128ull * 64 * 2);
    unsigned short* ve_t    = (unsigned short*)carve(64ull * 128 * 2);
    unsigned short* q_buf   = (unsigned short*)carve(65536ull * 64 * 2);    //  8 MB
    unsigned short* k_buf   = (unsigned short*)carve(65536ull * 64 * 2);    //  8 MB
    unsigned short* v_t     = (unsigned short*)carve(65536ull * 64 * 2);    //  8 MB
    unsigned short* q_proj  = (unsigned short*)carve(65536ull * 128 * 2);   // 16 MB
    unsigned short* k_proj  = (unsigned short*)carve(65536ull * 128 * 2);   // 16 MB
    unsigned short* kp_edge = (unsigned short*)carve(2ull * 65536 * 2);     // 256 KB
    unsigned short* attn_o  = x_bf;   // alias: x_bf dead after QKV gemm
    (void)ws_size; (void)in_sizes; (void)n_in; (void)out_size;              // ~72.3 MB

    convert_kernel<<<1537, 256, 0, stream>>>(x, wq, wk, wv, wo, qe, ke, ve,
                                             x_bf, wqkv_bt, wo_bt, qe_bf, ke_bf, ve_t);

    // QKV: [4096,1024] @ [1024,3072]; v transposed via LDS (coalesced)
    gemm_qkv_kernel<<<dim3(24, 32), 256, 0, stream>>>(
        x_bf, wqkv_bt, q_buf, k_buf, v_t);

    // merged q_proj + k_proj (+ kp_edge): one 1024-block launch
    proj_kernel<<<dim3(1, 1024), 256, 0, stream>>>(
        q_buf, k_buf, qe_bf, ke_bf, q_proj, k_proj, kp_edge);

    // fused attention (async DMA staging, 1 barrier/tile steady state)
    hipFuncSetAttribute((const void*)attn_kernel,
                        hipFuncAttributeMaxDynamicSharedMemorySize, ATTN_LDS_BYTES);
    attn_kernel<<<512, 512, ATTN_LDS_BYTES, stream>>>(
        q_buf, k_buf, v_t, q_proj, k_proj, kp_edge, ve_t, mask, attn_o);

    // output projection: 128x64 tiles, 512 blocks = 2/CU
    gemm_n64_kernel<<<dim3(16, 32), 256, 0, stream>>>(attn_o, wo_bt, (float*)d_out);
}